// Round 9
// baseline (3189.531 us; speedup 1.0000x reference)
//
#include <hip/hip_runtime.h>
#include <math.h>
#include <stdint.h>

#define B 1024
#define H 512
#define T_SRC 50
#define T_TGT 30
#define I_DIM 4
#define NTHR 256
#define NSTEP (T_SRC + T_TGT)

typedef _Float16 half8 __attribute__((ext_vector_type(8)));
typedef float f32x4 __attribute__((ext_vector_type(4)));
typedef unsigned long long u64;
typedef u64 u64x2 __attribute__((ext_vector_type(2)));

#define GLOBAL_AS __attribute__((address_space(1)))
#define LDS_AS    __attribute__((address_space(3)))

#define SCALE_F 1099511627776.0f          // 2^40 (fallback head fixed-point)

__device__ __forceinline__ float sigm(float x) { return 1.0f / (1.0f + expf(-x)); }

__device__ __forceinline__ void cohs(u64* p, u64 v) {
    __hip_atomic_store(p, v, __ATOMIC_RELAXED, __HIP_MEMORY_SCOPE_AGENT);
}

// ================= persistent path: panel-register GEMM =================

// Load a full 64x512 f16 A-panel slice into registers: 16 x dwordx4 per thread,
// all issued back-to-back -> single MALL latency exposure.
__device__ __forceinline__ void panel_load(u64x2 (&P)[8][2],
                                           const _Float16* __restrict__ base,
                                           const size_t* __restrict__ aoff)
{
#pragma unroll
    for (int kt = 0; kt < 8; ++kt)
#pragma unroll
        for (int q = 0; q < 2; ++q)
            P[kt][q] = *reinterpret_cast<const u64x2*>(base + aoff[q] + kt * 64);
}

// Force the panel to be materialized in VGPRs HERE (not sunk to use sites).
// Round-8 lesson: without this, the compiler re-issues the loads per-tile
// inside gemm_run (VGPR_Count was 124 < the 128 the panels require).
__device__ __forceinline__ void pin_panel(u64x2 (&P)[8][2])
{
#pragma unroll
    for (int kt = 0; kt < 8; ++kt)
#pragma unroll
        for (int q = 0; q < 2; ++q)
            asm volatile("" : "+v"(P[kt][q]));
}

// K-loop over NT8*8 tiles. A from register panels (ds_write staged, swizzled
// layout identical to the verified global_load_lds path), B via global_load_lds
// (L2-warm weights). Fully unrolled: every panel index is compile-time.
template<int NT8>
__device__ __forceinline__ void gemm_run(
    char* smem,
    const u64x2 (&PA1)[8][2], const _Float16* __restrict__ W1,
    const u64x2 (&PA2)[8][2], const _Float16* __restrict__ W2,
    f32x4 (&acc)[2][2],
    const size_t* __restrict__ boff, const int* __restrict__ awof,
    const int* __restrict__ ldsw, int mw, int nw, int l)
{
    const int NT = NT8 * 8;
    // stage tile 0 into buf0
#pragma unroll
    for (int q = 0; q < 2; ++q) {
        *reinterpret_cast<u64x2*>(smem + awof[q]) = PA1[0][q];
        __builtin_amdgcn_global_load_lds(
            (const GLOBAL_AS uint32_t*)(W1 + boff[q]),
            (LDS_AS uint32_t*)(smem + 8192 + ldsw[q]), 16, 0, 0);
    }
    __syncthreads();
#pragma unroll
    for (int kt = 0; kt < NT; ++kt) {
        if (kt + 1 < NT) {   // stage tile kt+1 into the other buffer
            char* dbase = smem + ((kt + 1) & 1) * 16384;
            const _Float16* Wp = ((kt + 1) < 8) ? W1 : W2;
#pragma unroll
            for (int q = 0; q < 2; ++q) {
                *reinterpret_cast<u64x2*>(dbase + awof[q]) =
                    ((kt + 1) < 8) ? PA1[(kt + 1) & 7][q] : PA2[(kt + 1) & 7][q];
                __builtin_amdgcn_global_load_lds(
                    (const GLOBAL_AS uint32_t*)(Wp + boff[q] + ((kt + 1) & 7) * 64),
                    (LDS_AS uint32_t*)(dbase + 8192 + ldsw[q]), 16, 0, 0);
            }
        }
        const char* ab = smem + (kt & 1) * 16384;
        const char* bb = ab + 8192;
#pragma unroll
        for (int ks = 0; ks < 2; ++ks) {
            half8 af[2], bf[2];
#pragma unroll
            for (int f = 0; f < 2; ++f) {
                const int gg = ks * 4 + (l >> 4);
                const int m = mw + f * 16 + (l & 15);
                af[f] = *reinterpret_cast<const half8*>(ab + m * 128 + ((gg ^ (m & 7)) * 16));
                const int n = nw + f * 16 + (l & 15);
                bf[f] = *reinterpret_cast<const half8*>(bb + n * 128 + ((gg ^ (n & 7)) * 16));
            }
#pragma unroll
            for (int fm = 0; fm < 2; ++fm)
#pragma unroll
                for (int fn = 0; fn < 2; ++fn)
                    acc[fm][fn] = __builtin_amdgcn_mfma_f32_16x16x32_f16(
                        af[fm], bf[fn], acc[fm][fn], 0, 0, 0);
        }
        __syncthreads();
    }
}

// Verified epilogue (rounds 2-7): stash gates, cell update, write-through h.
__device__ __forceinline__ void cell_epilogue(
    char* smem, f32x4 (&acc)[2][2],
    const float* __restrict__ xg, int xstride, const float* __restrict__ xl,
    const float* __restrict__ Wih, const float* __restrict__ bias,
    float* __restrict__ c_st, _Float16* __restrict__ h_out,
    int m0, int kc0, int zero_c, int mw, int nw, int l)
{
    const int tid = threadIdx.x;
    float* Gs = reinterpret_cast<float*>(smem);
#pragma unroll
    for (int fm = 0; fm < 2; ++fm)
#pragma unroll
        for (int fn = 0; fn < 2; ++fn)
#pragma unroll
            for (int r = 0; r < 4; ++r)
                Gs[(mw + fm * 16 + (l >> 4) * 4 + r) * 65 + nw + fn * 16 + (l & 15)] =
                    acc[fm][fn][r];
    __syncthreads();

    const int em = tid & 63;
    const int ekq = tid >> 6;
    const int brow = m0 + em;
    const int kbase = kc0 + ekq * 4;
    float g4[4][4];
#pragma unroll
    for (int gate = 0; gate < 4; ++gate)
#pragma unroll
        for (int j = 0; j < 4; ++j)
            g4[gate][j] = Gs[em * 65 + gate * 16 + ekq * 4 + j]
                        + bias[gate * H + kbase + j];
    if (Wih != nullptr) {
        float x0, x1, x2, x3;
        if (xl != nullptr) {
            x0 = xl[em * 4 + 0]; x1 = xl[em * 4 + 1];
            x2 = xl[em * 4 + 2]; x3 = xl[em * 4 + 3];
        } else {
            const float* xr = xg + (size_t)brow * xstride;
            x0 = xr[0]; x1 = xr[1]; x2 = xr[2]; x3 = xr[3];
        }
#pragma unroll
        for (int gate = 0; gate < 4; ++gate)
#pragma unroll
            for (int j = 0; j < 4; ++j) {
                const float* wv = &Wih[(size_t)(gate * H + kbase + j) * 4];
                g4[gate][j] += x0 * wv[0] + x1 * wv[1] + x2 * wv[2] + x3 * wv[3];
            }
    }
    size_t cidx = (size_t)brow * H + kbase;
    f32x4 cold;
    if (zero_c) { cold[0] = cold[1] = cold[2] = cold[3] = 0.f; }
    else        { cold = *reinterpret_cast<const f32x4*>(&c_st[cidx]); }
    f32x4 cnew;
    _Float16 h4[4];
#pragma unroll
    for (int j = 0; j < 4; ++j) {
        float cn = sigm(g4[1][j]) * cold[j] + sigm(g4[0][j]) * tanhf(g4[2][j]);
        cnew[j] = cn;
        h4[j] = (_Float16)(sigm(g4[3][j]) * tanhf(cn));
    }
    *reinterpret_cast<f32x4*>(&c_st[cidx]) = cnew;
    u64 hbits;
    __builtin_memcpy(&hbits, h4, 8);
    cohs(reinterpret_cast<u64*>(h_out + cidx), hbits);
}

struct PP {
    const float* x;
    const float* eWih0; const float* eb0; const float* eb1;
    const float* dWih0; const float* db0; const float* db1;
    const float* headW; const float* headb;
    const _Float16* eWhh0f; const _Float16* eWih1f; const _Float16* eWhh1f;
    const _Float16* dWhh0f; const _Float16* dWih1f; const _Float16* dWhh1f;
    float* c0; float* c1;
    _Float16* h0base;    // 80 x 1MB fresh buffers
    _Float16* h1base;
    uint32_t* flags;     // [16 groups][32 blocks] monotone counters, pre-zeroed
    float* outp;
};

// Flag-array barrier: 32 parallel stores (no RMW serialization) + one
// wave-parallel 32-lane poll. Monotone counters; no fences (write-through h +
// fresh-address reads provide data coherence — rounds 5/7 verified protocol).
__device__ __forceinline__ void bar_flags(uint32_t* gf, int ntile, uint32_t bar)
{
    __syncthreads();   // drains vmcnt(0): h stores reached coherence point
    if (threadIdx.x == 0)
        __hip_atomic_store(gf + ntile, bar, __ATOMIC_RELAXED, __HIP_MEMORY_SCOPE_AGENT);
    if (threadIdx.x < 32) {
        while (__hip_atomic_load(gf + (int)threadIdx.x, __ATOMIC_RELAXED,
                                 __HIP_MEMORY_SCOPE_AGENT) < bar)
            __builtin_amdgcn_s_sleep(1);
    }
    __syncthreads();
    asm volatile("" ::: "memory");
}

__device__ __forceinline__ void head_phase2(
    const _Float16* __restrict__ h1, const float* __restrict__ W,
    const float* __restrict__ hb, float* __restrict__ decb,
    float* __restrict__ outp, int m0, int t)
{
    const int tid = threadIdx.x;
    const int row = tid >> 2, o = tid & 3;
    const _Float16* hr = h1 + (size_t)(m0 + row) * H;
    const float* wr = W + o * H;
    float s = 0.f;
#pragma unroll 4
    for (int k = 0; k < H; k += 8) {
        half8 hv = *reinterpret_cast<const half8*>(hr + k);
#pragma unroll
        for (int j = 0; j < 8; ++j) s += (float)hv[j] * wr[k + j];
    }
    s += hb[o];
    decb[row * 4 + o] = s;
    if (outp != nullptr)
        outp[((size_t)(m0 + row) * T_TGT + t) * I_DIM + o] = s;
}

__global__ __launch_bounds__(NTHR, 2)
void lstm_persist4(PP P)
{
    __shared__ __align__(16) char smem[32768];
    __shared__ float decbuf[64 * 4];

    const int bx = blockIdx.x;
    const int sxcd = bx & 7;
    const int q = bx >> 3;
    const int lowq = q & 15;
    const int hi = (q >> 4) & 3;
    const int g = lowq ^ ((hi >> 1) << 3);
    const int ntile = sxcd * 4 + hi;
    const int m0 = g * 64;
    const int kc0 = ntile * 16;

    const int tid = threadIdx.x;
    const int w = tid >> 6, l = tid & 63;
    const int mw = (w & 1) * 32, nw = (w >> 1) * 32;

    size_t aoff[2], boff[2];
    int awof[2], ldsw[2];
#pragma unroll
    for (int qq = 0; qq < 2; ++qq) {
        int rowq = (w * 2 + qq) * 8 + (l >> 3);
        int gsrc = (l & 7) ^ (rowq & 7);
        aoff[qq] = (size_t)(m0 + rowq) * H + gsrc * 8;
        int jg = (rowq >> 4) * H + kc0 + (rowq & 15);
        boff[qq] = (size_t)jg * H + gsrc * 8;
        ldsw[qq] = (w * 2 + qq) * 1024;
        awof[qq] = ldsw[qq] + l * 16;
    }

    uint32_t* gf = P.flags + g * 32;
    uint32_t bar = 0;

    u64x2 ph0[8][2];   // h0(s) panel (loaded after barrier1; reused by next L0)
    u64x2 ph1[8][2];   // h1(s-1) panel (loaded after barrier2)

    auto h0buf = [&](int s) { return P.h0base + ((size_t)s << 19); };
    auto h1buf = [&](int s) { return P.h1base + ((size_t)s << 19); };

    for (int s = 0; s < NSTEP; ++s) {
        const bool enc = (s < T_SRC);
        // ---------------- layer 0 ----------------
        {
            f32x4 acc[2][2] = {};
            if (s > 0)
                gemm_run<1>(smem, ph0, enc ? P.eWhh0f : P.dWhh0f,
                            ph0, enc ? P.eWhh0f : P.dWhh0f,
                            acc, boff, awof, ldsw, mw, nw, l);
            const float* xg = nullptr; const float* xl = nullptr;
            if (enc)              xg = P.x + (size_t)s * I_DIM;
            else if (s == T_SRC)  xg = P.x + (size_t)(T_SRC - 1) * I_DIM;
            else                  xl = decbuf;
            cell_epilogue(smem, acc, xg, T_SRC * I_DIM, xl,
                          enc ? P.eWih0 : P.dWih0, enc ? P.eb0 : P.db0,
                          P.c0, h0buf(s), m0, kc0, (s == 0) ? 1 : 0, mw, nw, l);
        }
        bar_flags(gf, ntile, ++bar);
        panel_load(ph0, h0buf(s), aoff);   // h0(s): for L1 pass1 + next L0
        pin_panel(ph0);                    // materialize NOW (round-8 fix)
        // ---------------- layer 1 ----------------
        {
            f32x4 acc[2][2] = {};
            if (s == 0)
                gemm_run<1>(smem, ph0, P.eWih1f, ph0, P.eWih1f,
                            acc, boff, awof, ldsw, mw, nw, l);
            else
                // pass1 = h0(s)@Wih1, pass2 = h1(s-1)@Whh1 — rounds 2-7
                // accumulation order (round-8 swap cost 3x absmax margin)
                gemm_run<2>(smem, ph0, enc ? P.eWih1f : P.dWih1f,
                            ph1, enc ? P.eWhh1f : P.dWhh1f,
                            acc, boff, awof, ldsw, mw, nw, l);
            cell_epilogue(smem, acc, nullptr, 0, nullptr, nullptr,
                          enc ? P.eb1 : P.db1,
                          P.c1, h1buf(s), m0, kc0, (s == 0) ? 1 : 0, mw, nw, l);
        }
        bar_flags(gf, ntile, ++bar);
        panel_load(ph1, h1buf(s), aoff);   // h1(s): for next step's L1 pass2
        pin_panel(ph1);
        if (!enc) {
            head_phase2(h1buf(s), P.headW, P.headb, decbuf,
                        (ntile == 0) ? P.outp : nullptr, m0, s - T_SRC);
            __syncthreads();
        }
    }
}

// ================= fallback path (round-6 verified, unchanged) =================

__device__ __forceinline__ void layer_core(
    char* smem,
    const _Float16* __restrict__ A1, const _Float16* __restrict__ W1,
    const _Float16* __restrict__ A2, const _Float16* __restrict__ W2,
    int npass, int zero_c,
    const float* __restrict__ xg, int xstride,
    const float* __restrict__ xl,
    const float* __restrict__ Wih,
    const float* __restrict__ bias,
    float* __restrict__ c_st, _Float16* __restrict__ h_out,
    _Float16* pH,
    int m0, int kc0)
{
    const int tid = threadIdx.x;
    const int w = tid >> 6, l = tid & 63;
    const int mw = (w & 1) * 32, nw = (w >> 1) * 32;

    f32x4 acc[2][2] = {};
    const int nt = npass * 8;

    size_t aoff[2], boff[2];
    int ldsw[2];
#pragma unroll
    for (int q = 0; q < 2; ++q) {
        int rowq = (w * 2 + q) * 8 + (l >> 3);
        int gsrc = (l & 7) ^ (rowq & 7);
        aoff[q] = (size_t)(m0 + rowq) * H + gsrc * 8;
        int jg = (rowq >> 4) * H + kc0 + (rowq & 15);
        boff[q] = (size_t)jg * H + gsrc * 8;
        ldsw[q] = (w * 2 + q) * 1024;
    }

    auto stage = [&](int t, int cur) {
        const _Float16* Ap = (t < 8) ? A1 : A2;
        const _Float16* Wp = (t < 8) ? W1 : W2;
        const int koff = (t & 7) * 64;
        char* dbase = smem + cur * 16384;
#pragma unroll
        for (int q = 0; q < 2; ++q) {
            __builtin_amdgcn_global_load_lds(
                (const GLOBAL_AS uint32_t*)(Ap + aoff[q] + koff),
                (LDS_AS uint32_t*)(dbase + ldsw[q]), 16, 0, 0);
            __builtin_amdgcn_global_load_lds(
                (const GLOBAL_AS uint32_t*)(Wp + boff[q] + koff),
                (LDS_AS uint32_t*)(dbase + 8192 + ldsw[q]), 16, 0, 0);
        }
    };

    if (nt > 0) {
        stage(0, 0);
        __syncthreads();
        int cur = 0;
        for (int t = 0; t < nt; ++t) {
            if (t + 1 < nt) stage(t + 1, cur ^ 1);
            const char* ab = smem + cur * 16384;
            const char* bb = ab + 8192;
#pragma unroll
            for (int ks = 0; ks < 2; ++ks) {
                half8 af[2], bf[2];
#pragma unroll
                for (int f = 0; f < 2; ++f) {
                    const int gg = ks * 4 + (l >> 4);
                    const int m = mw + f * 16 + (l & 15);
                    af[f] = *reinterpret_cast<const half8*>(ab + m * 128 + ((gg ^ (m & 7)) * 16));
                    const int n = nw + f * 16 + (l & 15);
                    bf[f] = *reinterpret_cast<const half8*>(bb + n * 128 + ((gg ^ (n & 7)) * 16));
                }
#pragma unroll
                for (int fm = 0; fm < 2; ++fm)
#pragma unroll
                    for (int fn = 0; fn < 2; ++fn)
                        acc[fm][fn] = __builtin_amdgcn_mfma_f32_16x16x32_f16(
                            af[fm], bf[fn], acc[fm][fn], 0, 0, 0);
            }
            __syncthreads();
            cur ^= 1;
        }
    }

    float* Gs = reinterpret_cast<float*>(smem);
#pragma unroll
    for (int fm = 0; fm < 2; ++fm)
#pragma unroll
        for (int fn = 0; fn < 2; ++fn)
#pragma unroll
            for (int r = 0; r < 4; ++r)
                Gs[(mw + fm * 16 + (l >> 4) * 4 + r) * 65 + nw + fn * 16 + (l & 15)] =
                    acc[fm][fn][r];
    __syncthreads();

    {
        const int em = tid & 63;
        const int ekq = tid >> 6;
        const int brow = m0 + em;
        const int kbase = kc0 + ekq * 4;
        float g4[4][4];
#pragma unroll
        for (int gate = 0; gate < 4; ++gate)
#pragma unroll
            for (int j = 0; j < 4; ++j)
                g4[gate][j] = Gs[em * 65 + gate * 16 + ekq * 4 + j]
                            + bias[gate * H + kbase + j];
        if (Wih != nullptr) {
            float x0, x1, x2, x3;
            if (xl != nullptr) {
                x0 = xl[em * 4 + 0]; x1 = xl[em * 4 + 1];
                x2 = xl[em * 4 + 2]; x3 = xl[em * 4 + 3];
            } else {
                const float* xr = xg + (size_t)brow * xstride;
                x0 = xr[0]; x1 = xr[1]; x2 = xr[2]; x3 = xr[3];
            }
#pragma unroll
            for (int gate = 0; gate < 4; ++gate)
#pragma unroll
                for (int j = 0; j < 4; ++j) {
                    const float* wv = &Wih[(size_t)(gate * H + kbase + j) * 4];
                    g4[gate][j] += x0 * wv[0] + x1 * wv[1] + x2 * wv[2] + x3 * wv[3];
                }
        }
        size_t cidx = (size_t)brow * H + kbase;
        f32x4 cold;
        if (zero_c) { cold[0] = cold[1] = cold[2] = cold[3] = 0.f; }
        else        { cold = *reinterpret_cast<const f32x4*>(&c_st[cidx]); }
        f32x4 cnew;
        _Float16 h4[4];
#pragma unroll
        for (int j = 0; j < 4; ++j) {
            float cn = sigm(g4[1][j]) * cold[j] + sigm(g4[0][j]) * tanhf(g4[2][j]);
            cnew[j] = cn;
            h4[j] = (_Float16)(sigm(g4[3][j]) * tanhf(cn));
        }
        *reinterpret_cast<f32x4*>(&c_st[cidx]) = cnew;
        u64 hbits;
        __builtin_memcpy(&hbits, h4, 8);
        *reinterpret_cast<u64*>(h_out + cidx) = hbits;
        if (pH != nullptr) {
#pragma unroll
            for (int j = 0; j < 4; ++j)
                pH[em * 16 + ekq * 4 + j] = h4[j];
        }
    }
}

__global__ __launch_bounds__(NTHR)
void enc_step(int d, const float* __restrict__ x,
              const float* __restrict__ eWih0, const float* __restrict__ eb0,
              const float* __restrict__ eb1,
              const _Float16* __restrict__ eWhh0, const _Float16* __restrict__ eWih1,
              const _Float16* __restrict__ eWhh1,
              float* __restrict__ c0, float* __restrict__ c1,
              _Float16* h0a, _Float16* h0b, _Float16* h1a, _Float16* h1b)
{
    __shared__ __align__(16) char smem[32768];
    const int bx = blockIdx.x;
    const int role = bx >> 9, sub = bx & 511;
    const int m0 = (sub & 15) * 64, kc0 = (sub >> 4) * 16;
    _Float16* h0[2] = {h0a, h0b};
    _Float16* h1[2] = {h1a, h1b};

    if (role == 0) {
        const int t = d;
        if (t >= T_SRC) return;
        const _Float16* A1 = (t == 0) ? nullptr : h0[(t - 1) & 1];
        layer_core(smem, A1, eWhh0, nullptr, nullptr, (t == 0) ? 0 : 1, (t == 0) ? 1 : 0,
                   x + (size_t)t * I_DIM, T_SRC * I_DIM, nullptr,
                   eWih0, eb0, c0, h0[t & 1], nullptr, m0, kc0);
    } else {
        const int t = d - 1;
        if (t < 0) return;
        if (t == 0)
            layer_core(smem, h0[0], eWih1, nullptr, nullptr, 1, 1,
                       nullptr, 0, nullptr, nullptr, eb1, c1, h1[0], nullptr, m0, kc0);
        else
            layer_core(smem, h0[t & 1], eWih1, h1[(t - 1) & 1], eWhh1, 2, 0,
                       nullptr, 0, nullptr, nullptr, eb1, c1, h1[t & 1], nullptr, m0, kc0);
    }
}

__global__ __launch_bounds__(NTHR)
void dec0_step(int t, const float* __restrict__ x,
               const float* __restrict__ dWih0, const float* __restrict__ db0,
               const float* __restrict__ headb,
               const _Float16* __restrict__ dWhh0,
               float* __restrict__ c0,
               _Float16* h0a, _Float16* h0b,
               u64* __restrict__ accA, u64* __restrict__ accB,
               float* __restrict__ outp)
{
    __shared__ __align__(16) char smem[32768];
    __shared__ float decbuf[64 * 4];
    const int sub = blockIdx.x;
    const int m0 = (sub & 15) * 64, kc0 = (sub >> 4) * 16;
    const int ntile = sub >> 4;
    const int tid = threadIdx.x;
    _Float16* h0[2] = {h0a, h0b};

    u64* accCur = (t & 1) ? accB : accA;
    u64* accPrev = (t & 1) ? accA : accB;

    const int row = tid >> 2, o = tid & 3;
    if (ntile == 0)
        accCur[(size_t)(m0 + row) * I_DIM + o] = 0ull;

    const float* xg = nullptr;
    const float* xl = nullptr;
    if (t == 0) {
        xg = x + (size_t)(T_SRC - 1) * I_DIM;
    } else {
        long long v = (long long)accPrev[(size_t)(m0 + row) * I_DIM + o];
        float val = (float)((double)v * (1.0 / 1099511627776.0)) + headb[o];
        decbuf[tid] = val;
        if (ntile == 0)
            outp[((size_t)(m0 + row) * T_TGT + (t - 1)) * I_DIM + o] = val;
        xl = decbuf;
        __syncthreads();
    }

    const _Float16* A1 = (t == 0) ? h0[1] : h0[(t - 1) & 1];
    layer_core(smem, A1, dWhh0, nullptr, nullptr, 1, 0,
               xg, T_SRC * I_DIM, xl, dWih0, db0, c0, h0[t & 1], nullptr, m0, kc0);
}

__global__ __launch_bounds__(NTHR)
void dec1_step(int t, const float* __restrict__ db1,
               const float* __restrict__ headW,
               const _Float16* __restrict__ dWih1, const _Float16* __restrict__ dWhh1,
               float* __restrict__ c1,
               _Float16* h0a, _Float16* h0b, _Float16* h1a, _Float16* h1b,
               u64* __restrict__ accA, u64* __restrict__ accB)
{
    __shared__ __align__(16) char smem[32768];
    __shared__ _Float16 pH[64 * 16];
    const int sub = blockIdx.x;
    const int m0 = (sub & 15) * 64, kc0 = (sub >> 4) * 16;
    const int tid = threadIdx.x;
    _Float16* h0[2] = {h0a, h0b};
    _Float16* h1[2] = {h1a, h1b};

    const _Float16* h1prev = (t == 0) ? h1[1] : h1[(t - 1) & 1];
    layer_core(smem, h0[t & 1], dWih1, h1prev, dWhh1, 2, 0,
               nullptr, 0, nullptr, nullptr, db1, c1, h1[t & 1], pH, m0, kc0);
    __syncthreads();

    u64* accCur = (t & 1) ? accB : accA;
    const int em = tid >> 2, o = tid & 3;
    float s = 0.f;
#pragma unroll
    for (int j = 0; j < 16; ++j)
        s += (float)pH[em * 16 + j] * headW[(size_t)o * H + kc0 + j];
    long long qv = (long long)(s * SCALE_F);
    atomicAdd(accCur + ((size_t)(m0 + em) * I_DIM + o), (u64)qv);
}

__global__ __launch_bounds__(NTHR)
void final_out(const u64* __restrict__ accLast, const float* __restrict__ headb,
               float* __restrict__ outp)
{
    int i = blockIdx.x * blockDim.x + threadIdx.x;
    if (i < B * I_DIM) {
        int b = i >> 2, o = i & 3;
        long long v = (long long)accLast[i];
        float val = (float)((double)v * (1.0 / 1099511627776.0)) + headb[o];
        outp[((size_t)b * T_TGT + (T_TGT - 1)) * I_DIM + o] = val;
    }
}

// ---------------- shared setup kernels ----------------

__global__ void zero_kernel(float* __restrict__ ptr, int n)
{
    int i = blockIdx.x * blockDim.x + threadIdx.x;
    int stride = gridDim.x * blockDim.x;
    for (; i < n; i += stride) ptr[i] = 0.f;
}

__global__ void convert6(const float* __restrict__ s0, const float* __restrict__ s1,
                         const float* __restrict__ s2, const float* __restrict__ s3,
                         const float* __restrict__ s4, const float* __restrict__ s5,
                         _Float16* __restrict__ dst)
{
    const int WN4 = (1 << 20) / 4;
    int i = blockIdx.x * blockDim.x + threadIdx.x;
    int stride = gridDim.x * blockDim.x;
    for (; i < 6 * WN4; i += stride) {
        int seg = i / WN4;
        int off = i - seg * WN4;
        const float* sp = seg == 0 ? s0 : seg == 1 ? s1 : seg == 2 ? s2
                        : seg == 3 ? s3 : seg == 4 ? s4 : s5;
        float4 v = reinterpret_cast<const float4*>(sp)[off];
        _Float16 h4o[4] = {(_Float16)v.x, (_Float16)v.y, (_Float16)v.z, (_Float16)v.w};
        u64 bits;
        __builtin_memcpy(&bits, h4o, 8);
        reinterpret_cast<u64*>(dst)[i] = bits;
    }
}

extern "C" void kernel_launch(void* const* d_in, const int* in_sizes, int n_in,
                              void* d_out, int out_size, void* d_ws, size_t ws_size,
                              hipStream_t stream)
{
    const float* x        = (const float*)d_in[0];
    const float* enc_Wih0 = (const float*)d_in[1];
    const float* enc_Whh0 = (const float*)d_in[2];
    const float* enc_b0   = (const float*)d_in[3];
    const float* enc_Wih1 = (const float*)d_in[4];
    const float* enc_Whh1 = (const float*)d_in[5];
    const float* enc_b1   = (const float*)d_in[6];
    const float* dec_Wih0 = (const float*)d_in[7];
    const float* dec_Whh0 = (const float*)d_in[8];
    const float* dec_b0   = (const float*)d_in[9];
    const float* dec_Wih1 = (const float*)d_in[10];
    const float* dec_Whh1 = (const float*)d_in[11];
    const float* dec_b1   = (const float*)d_in[12];
    const float* head_W   = (const float*)d_in[13];
    const float* head_b   = (const float*)d_in[14];
    float* out = (float*)d_out;

    const size_t MB = 1u << 20;
    char* ws = (char*)d_ws;
    const size_t PERSIST_NEED = 177 * MB;

    if (ws_size >= PERSIST_NEED) {
        float*    c0     = (float*)(ws + 0 * MB);
        float*    c1     = (float*)(ws + 2 * MB);
        uint32_t* flags  = (uint32_t*)(ws + 4 * MB);     // 16 x 32 u32
        _Float16* wf16   = (_Float16*)(ws + 5 * MB);     // 12MB
        _Float16* h0base = (_Float16*)(ws + 17 * MB);    // 80MB
        _Float16* h1base = (_Float16*)(ws + 97 * MB);    // 80MB

        zero_kernel<<<1, 256, 0, stream>>>((float*)flags, 1024);
        convert6<<<2048, NTHR, 0, stream>>>(enc_Whh0, enc_Wih1, enc_Whh1,
                                            dec_Whh0, dec_Wih1, dec_Whh1, wf16);

        PP P;
        P.x = x;
        P.eWih0 = enc_Wih0; P.eb0 = enc_b0; P.eb1 = enc_b1;
        P.dWih0 = dec_Wih0; P.db0 = dec_b0; P.db1 = dec_b1;
        P.headW = head_W; P.headb = head_b;
        P.eWhh0f = wf16 + 0 * (1 << 20);
        P.eWih1f = wf16 + 1 * (1 << 20);
        P.eWhh1f = wf16 + 2 * (1 << 20);
        P.dWhh0f = wf16 + 3 * (1 << 20);
        P.dWih1f = wf16 + 4 * (1 << 20);
        P.dWhh1f = wf16 + 5 * (1 << 20);
        P.c0 = c0; P.c1 = c1;
        P.h0base = h0base; P.h1base = h1base;
        P.flags = flags;
        P.outp = out;

        lstm_persist4<<<dim3(512), dim3(NTHR), 0, stream>>>(P);
        return;
    }

    // fallback: round-6 multi-launch
    float*    c0     = (float*)(ws + 0 * MB);
    float*    c1     = (float*)(ws + 2 * MB);
    _Float16* h0a    = (_Float16*)(ws + 4 * MB);
    _Float16* h0b    = (_Float16*)(ws + 5 * MB);
    _Float16* h1a    = (_Float16*)(ws + 6 * MB);
    _Float16* h1b    = (_Float16*)(ws + 7 * MB);
    u64*      accA   = (u64*)(ws + 8 * MB);
    u64*      accB   = (u64*)(ws + 8 * MB + 65536);
    _Float16* wf16   = (_Float16*)(ws + 9 * MB);

    convert6<<<2048, NTHR, 0, stream>>>(enc_Whh0, enc_Wih1, enc_Whh1,
                                        dec_Whh0, dec_Wih1, dec_Whh1, wf16);
    _Float16* eWhh0f = wf16 + 0 * (1 << 20);
    _Float16* eWih1f = wf16 + 1 * (1 << 20);
    _Float16* eWhh1f = wf16 + 2 * (1 << 20);
    _Float16* dWhh0f = wf16 + 3 * (1 << 20);
    _Float16* dWih1f = wf16 + 4 * (1 << 20);
    _Float16* dWhh1f = wf16 + 5 * (1 << 20);

    for (int d = 0; d <= T_SRC; ++d)
        enc_step<<<1024, NTHR, 0, stream>>>(d, x, enc_Wih0, enc_b0, enc_b1,
                                            eWhh0f, eWih1f, eWhh1f,
                                            c0, c1, h0a, h0b, h1a, h1b);

    for (int t = 0; t < T_TGT; ++t) {
        dec0_step<<<512, NTHR, 0, stream>>>(t, x, dec_Wih0, dec_b0, head_b,
                                            dWhh0f, c0, h0a, h0b, accA, accB, out);
        dec1_step<<<512, NTHR, 0, stream>>>(t, dec_b1, head_W, dWih1f, dWhh1f,
                                            c1, h0a, h0b, h1a, h1b, accA, accB);
    }
    final_out<<<(B * I_DIM + NTHR - 1) / NTHR, NTHR, 0, stream>>>(
        (T_TGT - 1) & 1 ? accB : accA, head_b, out);
}

// Round 10
// 2699.532 us; speedup vs baseline: 1.1815x; 1.1815x over previous
//
#include <hip/hip_runtime.h>
#include <math.h>
#include <stdint.h>

#define B 1024
#define H 512
#define T_SRC 50
#define T_TGT 30
#define I_DIM 4
#define NTHR 256
#define NSTEP (T_SRC + T_TGT)

typedef _Float16 half8 __attribute__((ext_vector_type(8)));
typedef float f32x4 __attribute__((ext_vector_type(4)));
typedef unsigned long long u64;

#define GLOBAL_AS __attribute__((address_space(1)))
#define LDS_AS    __attribute__((address_space(3)))

#define SCALE_F 1099511627776.0f          // 2^40 (fallback head fixed-point)

__device__ __forceinline__ float sigm(float x) { return 1.0f / (1.0f + expf(-x)); }

__device__ __forceinline__ void cohs(u64* p, u64 v) {
    __hip_atomic_store(p, v, __ATOMIC_RELAXED, __HIP_MEMORY_SCOPE_AGENT);
}

// ============== persistent path: counted-vmcnt pipelined GEMM ==============
// T3/T4 (learn_hip m218): ring of 4 LDS buffers, 3 tiles in flight, counted
// s_waitcnt vmcnt(N) + raw s_barrier. Per-wave loads/tile = 4 (2 A + 2 B),
// identical across waves, so vmcnt counting is uniform. vmcnt retires in
// issue order (m135), so vmcnt(8) with 12 outstanding = oldest tile done.
// Staged bytes / swizzle / MFMA order byte-identical to the r7-verified core.
template<int NT8>
__device__ __forceinline__ void gemm_run(
    char* smem,
    const _Float16* __restrict__ A1, const _Float16* __restrict__ W1,
    const _Float16* __restrict__ A2, const _Float16* __restrict__ W2,
    f32x4 (&acc)[2][2],
    const size_t* __restrict__ aoff, const size_t* __restrict__ boff,
    const int* __restrict__ ldsw, int mw, int nw, int l)
{
    const int NT = NT8 * 8;

    auto issue = [&](int t) {
        const _Float16* Ap = (t < 8) ? A1 : A2;
        const _Float16* Wp = (t < 8) ? W1 : W2;
        const int koff = (t & 7) * 64;
        char* dbase = smem + (t & 3) * 16384;
#pragma unroll
        for (int q = 0; q < 2; ++q) {
            __builtin_amdgcn_global_load_lds(
                (const GLOBAL_AS uint32_t*)(Ap + aoff[q] + koff),
                (LDS_AS uint32_t*)(dbase + ldsw[q]), 16, 0, 0);
            __builtin_amdgcn_global_load_lds(
                (const GLOBAL_AS uint32_t*)(Wp + boff[q] + koff),
                (LDS_AS uint32_t*)(dbase + 8192 + ldsw[q]), 16, 0, 0);
        }
    };

    issue(0); issue(1); issue(2);   // 12 loads in flight

#pragma unroll
    for (int t = 0; t < NT; ++t) {
        // wait for tile t's 4 loads (the oldest), keep up to 8 newer in flight
        if (t <= NT - 3)      asm volatile("s_waitcnt vmcnt(8)" ::: "memory");
        else if (t == NT - 2) asm volatile("s_waitcnt vmcnt(4)" ::: "memory");
        else                  asm volatile("s_waitcnt vmcnt(0)" ::: "memory");
        __builtin_amdgcn_s_barrier();   // all waves' tile-t chunks now in LDS
        // safe to overwrite buffer (t+3)&3 == (t-1)&3: reads of t-1 finished
        // before this barrier (MFMA lgkm deps forced them last iteration)
        if (t + 3 < NT) issue(t + 3);

        const char* ab = smem + (t & 3) * 16384;
        const char* bb = ab + 8192;
#pragma unroll
        for (int ks = 0; ks < 2; ++ks) {
            half8 af[2], bf[2];
#pragma unroll
            for (int f = 0; f < 2; ++f) {
                const int gg = ks * 4 + (l >> 4);
                const int m = mw + f * 16 + (l & 15);
                af[f] = *reinterpret_cast<const half8*>(ab + m * 128 + ((gg ^ (m & 7)) * 16));
                const int n = nw + f * 16 + (l & 15);
                bf[f] = *reinterpret_cast<const half8*>(bb + n * 128 + ((gg ^ (n & 7)) * 16));
            }
#pragma unroll
            for (int fm = 0; fm < 2; ++fm)
#pragma unroll
                for (int fn = 0; fn < 2; ++fn)
                    acc[fm][fn] = __builtin_amdgcn_mfma_f32_16x16x32_f16(
                        af[fm], bf[fn], acc[fm][fn], 0, 0, 0);
        }
    }
    __syncthreads();   // all reads done before smem is reused for Gs
}

// Verified epilogue (rounds 2-7): stash gates, cell update, write-through h.
__device__ __forceinline__ void cell_epilogue(
    char* smem, f32x4 (&acc)[2][2],
    const float* __restrict__ xg, int xstride, const float* __restrict__ xl,
    const float* __restrict__ Wih, const float* __restrict__ bias,
    float* __restrict__ c_st, _Float16* __restrict__ h_out,
    int m0, int kc0, int zero_c, int mw, int nw, int l)
{
    const int tid = threadIdx.x;
    float* Gs = reinterpret_cast<float*>(smem);
#pragma unroll
    for (int fm = 0; fm < 2; ++fm)
#pragma unroll
        for (int fn = 0; fn < 2; ++fn)
#pragma unroll
            for (int r = 0; r < 4; ++r)
                Gs[(mw + fm * 16 + (l >> 4) * 4 + r) * 65 + nw + fn * 16 + (l & 15)] =
                    acc[fm][fn][r];
    __syncthreads();

    const int em = tid & 63;
    const int ekq = tid >> 6;
    const int brow = m0 + em;
    const int kbase = kc0 + ekq * 4;
    float g4[4][4];
#pragma unroll
    for (int gate = 0; gate < 4; ++gate)
#pragma unroll
        for (int j = 0; j < 4; ++j)
            g4[gate][j] = Gs[em * 65 + gate * 16 + ekq * 4 + j]
                        + bias[gate * H + kbase + j];
    if (Wih != nullptr) {
        float x0, x1, x2, x3;
        if (xl != nullptr) {
            x0 = xl[em * 4 + 0]; x1 = xl[em * 4 + 1];
            x2 = xl[em * 4 + 2]; x3 = xl[em * 4 + 3];
        } else {
            const float* xr = xg + (size_t)brow * xstride;
            x0 = xr[0]; x1 = xr[1]; x2 = xr[2]; x3 = xr[3];
        }
#pragma unroll
        for (int gate = 0; gate < 4; ++gate)
#pragma unroll
            for (int j = 0; j < 4; ++j) {
                const float* wv = &Wih[(size_t)(gate * H + kbase + j) * 4];
                g4[gate][j] += x0 * wv[0] + x1 * wv[1] + x2 * wv[2] + x3 * wv[3];
            }
    }
    size_t cidx = (size_t)brow * H + kbase;
    f32x4 cold;
    if (zero_c) { cold[0] = cold[1] = cold[2] = cold[3] = 0.f; }
    else        { cold = *reinterpret_cast<const f32x4*>(&c_st[cidx]); }
    f32x4 cnew;
    _Float16 h4[4];
#pragma unroll
    for (int j = 0; j < 4; ++j) {
        float cn = sigm(g4[1][j]) * cold[j] + sigm(g4[0][j]) * tanhf(g4[2][j]);
        cnew[j] = cn;
        h4[j] = (_Float16)(sigm(g4[3][j]) * tanhf(cn));
    }
    *reinterpret_cast<f32x4*>(&c_st[cidx]) = cnew;
    u64 hbits;
    __builtin_memcpy(&hbits, h4, 8);
    cohs(reinterpret_cast<u64*>(h_out + cidx), hbits);
}

struct PP {
    const float* x;
    const float* eWih0; const float* eb0; const float* eb1;
    const float* dWih0; const float* db0; const float* db1;
    const float* headW; const float* headb;
    const _Float16* eWhh0f; const _Float16* eWih1f; const _Float16* eWhh1f;
    const _Float16* dWhh0f; const _Float16* dWih1f; const _Float16* dWhh1f;
    float* c0; float* c1;
    _Float16* h0base;    // 80 x 1MB fresh buffers
    _Float16* h1base;
    uint32_t* flags;     // 16 groups x 64 u32 (monotone counters), pre-zeroed
    float* outp;
};

// r7-verified barrier: monotone counter, relaxed arrive + relaxed poll.
// No cache fences — h coherence = write-through stores + fresh-address reads.
__device__ __forceinline__ void grp_barrier2(uint32_t* cnt, uint32_t target)
{
    __syncthreads();
    if (threadIdx.x == 0) {
        __hip_atomic_fetch_add(cnt, 1u, __ATOMIC_RELAXED, __HIP_MEMORY_SCOPE_AGENT);
        while (__hip_atomic_load(cnt, __ATOMIC_RELAXED, __HIP_MEMORY_SCOPE_AGENT) < target)
            __builtin_amdgcn_s_sleep(2);
    }
    __syncthreads();
    asm volatile("" ::: "memory");
}

__device__ __forceinline__ void head_phase2(
    const _Float16* __restrict__ h1, const float* __restrict__ W,
    const float* __restrict__ hb, float* __restrict__ decb,
    float* __restrict__ outp, int m0, int t)
{
    const int tid = threadIdx.x;
    const int row = tid >> 2, o = tid & 3;
    const _Float16* hr = h1 + (size_t)(m0 + row) * H;
    const float* wr = W + o * H;
    float s = 0.f;
#pragma unroll 4
    for (int k = 0; k < H; k += 8) {
        half8 hv = *reinterpret_cast<const half8*>(hr + k);
#pragma unroll
        for (int j = 0; j < 8; ++j) s += (float)hv[j] * wr[k + j];
    }
    s += hb[o];
    decb[row * 4 + o] = s;
    if (outp != nullptr)
        outp[((size_t)(m0 + row) * T_TGT + t) * I_DIM + o] = s;
}

__global__ __launch_bounds__(NTHR, 2)
void lstm_persist5(PP P)
{
    __shared__ __align__(16) char smem[65536];   // 4-buffer ring
    __shared__ float decbuf[64 * 4];

    const int bx = blockIdx.x;
    const int sxcd = bx & 7;
    const int q = bx >> 3;
    const int lowq = q & 15;
    const int hi = (q >> 4) & 3;
    const int g = lowq ^ ((hi >> 1) << 3);
    const int ntile = sxcd * 4 + hi;
    const int m0 = g * 64;
    const int kc0 = ntile * 16;

    const int tid = threadIdx.x;
    const int w = tid >> 6, l = tid & 63;
    const int mw = (w & 1) * 32, nw = (w >> 1) * 32;

    size_t aoff[2], boff[2];
    int ldsw[2];
#pragma unroll
    for (int qq = 0; qq < 2; ++qq) {
        int rowq = (w * 2 + qq) * 8 + (l >> 3);
        int gsrc = (l & 7) ^ (rowq & 7);
        aoff[qq] = (size_t)(m0 + rowq) * H + gsrc * 8;
        int jg = (rowq >> 4) * H + kc0 + (rowq & 15);
        boff[qq] = (size_t)jg * H + gsrc * 8;
        ldsw[qq] = (w * 2 + qq) * 1024;
    }

    uint32_t* cnt = P.flags + g * 64;
    uint32_t bar = 0;

    auto h0buf = [&](int s) { return P.h0base + ((size_t)s << 19); };
    auto h1buf = [&](int s) { return P.h1base + ((size_t)s << 19); };

    for (int s = 0; s < NSTEP; ++s) {
        const bool enc = (s < T_SRC);
        // ---------------- layer 0 ----------------
        {
            f32x4 acc[2][2] = {};
            if (s > 0) {
                const _Float16* Wh0 = enc ? P.eWhh0f : P.dWhh0f;
                gemm_run<1>(smem, h0buf(s - 1), Wh0, h0buf(s - 1), Wh0,
                            acc, aoff, boff, ldsw, mw, nw, l);
            }
            const float* xg = nullptr; const float* xl = nullptr;
            if (enc)              xg = P.x + (size_t)s * I_DIM;
            else if (s == T_SRC)  xg = P.x + (size_t)(T_SRC - 1) * I_DIM;
            else                  xl = decbuf;
            cell_epilogue(smem, acc, xg, T_SRC * I_DIM, xl,
                          enc ? P.eWih0 : P.dWih0, enc ? P.eb0 : P.db0,
                          P.c0, h0buf(s), m0, kc0, (s == 0) ? 1 : 0, mw, nw, l);
        }
        grp_barrier2(cnt, 32u * (++bar));
        // ---------------- layer 1 ----------------
        {
            f32x4 acc[2][2] = {};
            if (s == 0)
                gemm_run<1>(smem, h0buf(0), P.eWih1f, h0buf(0), P.eWih1f,
                            acc, aoff, boff, ldsw, mw, nw, l);
            else
                // pass1 = h0(s)@Wih1, pass2 = h1(s-1)@Whh1 (rounds 2-7 order)
                gemm_run<2>(smem, h0buf(s), enc ? P.eWih1f : P.dWih1f,
                            h1buf(s - 1), enc ? P.eWhh1f : P.dWhh1f,
                            acc, aoff, boff, ldsw, mw, nw, l);
            cell_epilogue(smem, acc, nullptr, 0, nullptr, nullptr,
                          enc ? P.eb1 : P.db1,
                          P.c1, h1buf(s), m0, kc0, (s == 0) ? 1 : 0, mw, nw, l);
        }
        grp_barrier2(cnt, 32u * (++bar));
        if (!enc) {
            head_phase2(h1buf(s), P.headW, P.headb, decbuf,
                        (ntile == 0) ? P.outp : nullptr, m0, s - T_SRC);
            __syncthreads();
        }
    }
}

// ================= fallback path (round-6 verified, unchanged) =================

__device__ __forceinline__ void layer_core(
    char* smem,
    const _Float16* __restrict__ A1, const _Float16* __restrict__ W1,
    const _Float16* __restrict__ A2, const _Float16* __restrict__ W2,
    int npass, int zero_c,
    const float* __restrict__ xg, int xstride,
    const float* __restrict__ xl,
    const float* __restrict__ Wih,
    const float* __restrict__ bias,
    float* __restrict__ c_st, _Float16* __restrict__ h_out,
    _Float16* pH,
    int m0, int kc0)
{
    const int tid = threadIdx.x;
    const int w = tid >> 6, l = tid & 63;
    const int mw = (w & 1) * 32, nw = (w >> 1) * 32;

    f32x4 acc[2][2] = {};
    const int nt = npass * 8;

    size_t aoff[2], boff[2];
    int ldsw[2];
#pragma unroll
    for (int q = 0; q < 2; ++q) {
        int rowq = (w * 2 + q) * 8 + (l >> 3);
        int gsrc = (l & 7) ^ (rowq & 7);
        aoff[q] = (size_t)(m0 + rowq) * H + gsrc * 8;
        int jg = (rowq >> 4) * H + kc0 + (rowq & 15);
        boff[q] = (size_t)jg * H + gsrc * 8;
        ldsw[q] = (w * 2 + q) * 1024;
    }

    auto stage = [&](int t, int cur) {
        const _Float16* Ap = (t < 8) ? A1 : A2;
        const _Float16* Wp = (t < 8) ? W1 : W2;
        const int koff = (t & 7) * 64;
        char* dbase = smem + cur * 16384;
#pragma unroll
        for (int q = 0; q < 2; ++q) {
            __builtin_amdgcn_global_load_lds(
                (const GLOBAL_AS uint32_t*)(Ap + aoff[q] + koff),
                (LDS_AS uint32_t*)(dbase + ldsw[q]), 16, 0, 0);
            __builtin_amdgcn_global_load_lds(
                (const GLOBAL_AS uint32_t*)(Wp + boff[q] + koff),
                (LDS_AS uint32_t*)(dbase + 8192 + ldsw[q]), 16, 0, 0);
        }
    };

    if (nt > 0) {
        stage(0, 0);
        __syncthreads();
        int cur = 0;
        for (int t = 0; t < nt; ++t) {
            if (t + 1 < nt) stage(t + 1, cur ^ 1);
            const char* ab = smem + cur * 16384;
            const char* bb = ab + 8192;
#pragma unroll
            for (int ks = 0; ks < 2; ++ks) {
                half8 af[2], bf[2];
#pragma unroll
                for (int f = 0; f < 2; ++f) {
                    const int gg = ks * 4 + (l >> 4);
                    const int m = mw + f * 16 + (l & 15);
                    af[f] = *reinterpret_cast<const half8*>(ab + m * 128 + ((gg ^ (m & 7)) * 16));
                    const int n = nw + f * 16 + (l & 15);
                    bf[f] = *reinterpret_cast<const half8*>(bb + n * 128 + ((gg ^ (n & 7)) * 16));
                }
#pragma unroll
                for (int fm = 0; fm < 2; ++fm)
#pragma unroll
                    for (int fn = 0; fn < 2; ++fn)
                        acc[fm][fn] = __builtin_amdgcn_mfma_f32_16x16x32_f16(
                            af[fm], bf[fn], acc[fm][fn], 0, 0, 0);
            }
            __syncthreads();
            cur ^= 1;
        }
    }

    float* Gs = reinterpret_cast<float*>(smem);
#pragma unroll
    for (int fm = 0; fm < 2; ++fm)
#pragma unroll
        for (int fn = 0; fn < 2; ++fn)
#pragma unroll
            for (int r = 0; r < 4; ++r)
                Gs[(mw + fm * 16 + (l >> 4) * 4 + r) * 65 + nw + fn * 16 + (l & 15)] =
                    acc[fm][fn][r];
    __syncthreads();

    {
        const int em = tid & 63;
        const int ekq = tid >> 6;
        const int brow = m0 + em;
        const int kbase = kc0 + ekq * 4;
        float g4[4][4];
#pragma unroll
        for (int gate = 0; gate < 4; ++gate)
#pragma unroll
            for (int j = 0; j < 4; ++j)
                g4[gate][j] = Gs[em * 65 + gate * 16 + ekq * 4 + j]
                            + bias[gate * H + kbase + j];
        if (Wih != nullptr) {
            float x0, x1, x2, x3;
            if (xl != nullptr) {
                x0 = xl[em * 4 + 0]; x1 = xl[em * 4 + 1];
                x2 = xl[em * 4 + 2]; x3 = xl[em * 4 + 3];
            } else {
                const float* xr = xg + (size_t)brow * xstride;
                x0 = xr[0]; x1 = xr[1]; x2 = xr[2]; x3 = xr[3];
            }
#pragma unroll
            for (int gate = 0; gate < 4; ++gate)
#pragma unroll
                for (int j = 0; j < 4; ++j) {
                    const float* wv = &Wih[(size_t)(gate * H + kbase + j) * 4];
                    g4[gate][j] += x0 * wv[0] + x1 * wv[1] + x2 * wv[2] + x3 * wv[3];
                }
        }
        size_t cidx = (size_t)brow * H + kbase;
        f32x4 cold;
        if (zero_c) { cold[0] = cold[1] = cold[2] = cold[3] = 0.f; }
        else        { cold = *reinterpret_cast<const f32x4*>(&c_st[cidx]); }
        f32x4 cnew;
        _Float16 h4[4];
#pragma unroll
        for (int j = 0; j < 4; ++j) {
            float cn = sigm(g4[1][j]) * cold[j] + sigm(g4[0][j]) * tanhf(g4[2][j]);
            cnew[j] = cn;
            h4[j] = (_Float16)(sigm(g4[3][j]) * tanhf(cn));
        }
        *reinterpret_cast<f32x4*>(&c_st[cidx]) = cnew;
        u64 hbits;
        __builtin_memcpy(&hbits, h4, 8);
        *reinterpret_cast<u64*>(h_out + cidx) = hbits;
        if (pH != nullptr) {
#pragma unroll
            for (int j = 0; j < 4; ++j)
                pH[em * 16 + ekq * 4 + j] = h4[j];
        }
    }
}

__global__ __launch_bounds__(NTHR)
void enc_step(int d, const float* __restrict__ x,
              const float* __restrict__ eWih0, const float* __restrict__ eb0,
              const float* __restrict__ eb1,
              const _Float16* __restrict__ eWhh0, const _Float16* __restrict__ eWih1,
              const _Float16* __restrict__ eWhh1,
              float* __restrict__ c0, float* __restrict__ c1,
              _Float16* h0a, _Float16* h0b, _Float16* h1a, _Float16* h1b)
{
    __shared__ __align__(16) char smem[32768];
    const int bx = blockIdx.x;
    const int role = bx >> 9, sub = bx & 511;
    const int m0 = (sub & 15) * 64, kc0 = (sub >> 4) * 16;
    _Float16* h0[2] = {h0a, h0b};
    _Float16* h1[2] = {h1a, h1b};

    if (role == 0) {
        const int t = d;
        if (t >= T_SRC) return;
        const _Float16* A1 = (t == 0) ? nullptr : h0[(t - 1) & 1];
        layer_core(smem, A1, eWhh0, nullptr, nullptr, (t == 0) ? 0 : 1, (t == 0) ? 1 : 0,
                   x + (size_t)t * I_DIM, T_SRC * I_DIM, nullptr,
                   eWih0, eb0, c0, h0[t & 1], nullptr, m0, kc0);
    } else {
        const int t = d - 1;
        if (t < 0) return;
        if (t == 0)
            layer_core(smem, h0[0], eWih1, nullptr, nullptr, 1, 1,
                       nullptr, 0, nullptr, nullptr, eb1, c1, h1[0], nullptr, m0, kc0);
        else
            layer_core(smem, h0[t & 1], eWih1, h1[(t - 1) & 1], eWhh1, 2, 0,
                       nullptr, 0, nullptr, nullptr, eb1, c1, h1[t & 1], nullptr, m0, kc0);
    }
}

__global__ __launch_bounds__(NTHR)
void dec0_step(int t, const float* __restrict__ x,
               const float* __restrict__ dWih0, const float* __restrict__ db0,
               const float* __restrict__ headb,
               const _Float16* __restrict__ dWhh0,
               float* __restrict__ c0,
               _Float16* h0a, _Float16* h0b,
               u64* __restrict__ accA, u64* __restrict__ accB,
               float* __restrict__ outp)
{
    __shared__ __align__(16) char smem[32768];
    __shared__ float decbuf[64 * 4];
    const int sub = blockIdx.x;
    const int m0 = (sub & 15) * 64, kc0 = (sub >> 4) * 16;
    const int ntile = sub >> 4;
    const int tid = threadIdx.x;
    _Float16* h0[2] = {h0a, h0b};

    u64* accCur = (t & 1) ? accB : accA;
    u64* accPrev = (t & 1) ? accA : accB;

    const int row = tid >> 2, o = tid & 3;
    if (ntile == 0)
        accCur[(size_t)(m0 + row) * I_DIM + o] = 0ull;

    const float* xg = nullptr;
    const float* xl = nullptr;
    if (t == 0) {
        xg = x + (size_t)(T_SRC - 1) * I_DIM;
    } else {
        long long v = (long long)accPrev[(size_t)(m0 + row) * I_DIM + o];
        float val = (float)((double)v * (1.0 / 1099511627776.0)) + headb[o];
        decbuf[tid] = val;
        if (ntile == 0)
            outp[((size_t)(m0 + row) * T_TGT + (t - 1)) * I_DIM + o] = val;
        xl = decbuf;
        __syncthreads();
    }

    const _Float16* A1 = (t == 0) ? h0[1] : h0[(t - 1) & 1];
    layer_core(smem, A1, dWhh0, nullptr, nullptr, 1, 0,
               xg, T_SRC * I_DIM, xl, dWih0, db0, c0, h0[t & 1], nullptr, m0, kc0);
}

__global__ __launch_bounds__(NTHR)
void dec1_step(int t, const float* __restrict__ db1,
               const float* __restrict__ headW,
               const _Float16* __restrict__ dWih1, const _Float16* __restrict__ dWhh1,
               float* __restrict__ c1,
               _Float16* h0a, _Float16* h0b, _Float16* h1a, _Float16* h1b,
               u64* __restrict__ accA, u64* __restrict__ accB)
{
    __shared__ __align__(16) char smem[32768];
    __shared__ _Float16 pH[64 * 16];
    const int sub = blockIdx.x;
    const int m0 = (sub & 15) * 64, kc0 = (sub >> 4) * 16;
    const int tid = threadIdx.x;
    _Float16* h0[2] = {h0a, h0b};
    _Float16* h1[2] = {h1a, h1b};

    const _Float16* h1prev = (t == 0) ? h1[1] : h1[(t - 1) & 1];
    layer_core(smem, h0[t & 1], dWih1, h1prev, dWhh1, 2, 0,
               nullptr, 0, nullptr, nullptr, db1, c1, h1[t & 1], pH, m0, kc0);
    __syncthreads();

    u64* accCur = (t & 1) ? accB : accA;
    const int em = tid >> 2, o = tid & 3;
    float s = 0.f;
#pragma unroll
    for (int j = 0; j < 16; ++j)
        s += (float)pH[em * 16 + j] * headW[(size_t)o * H + kc0 + j];
    long long qv = (long long)(s * SCALE_F);
    atomicAdd(accCur + ((size_t)(m0 + em) * I_DIM + o), (u64)qv);
}

__global__ __launch_bounds__(NTHR)
void final_out(const u64* __restrict__ accLast, const float* __restrict__ headb,
               float* __restrict__ outp)
{
    int i = blockIdx.x * blockDim.x + threadIdx.x;
    if (i < B * I_DIM) {
        int b = i >> 2, o = i & 3;
        long long v = (long long)accLast[i];
        float val = (float)((double)v * (1.0 / 1099511627776.0)) + headb[o];
        outp[((size_t)b * T_TGT + (T_TGT - 1)) * I_DIM + o] = val;
    }
}

// ---------------- shared setup kernels ----------------

__global__ void zero_kernel(float* __restrict__ ptr, int n)
{
    int i = blockIdx.x * blockDim.x + threadIdx.x;
    int stride = gridDim.x * blockDim.x;
    for (; i < n; i += stride) ptr[i] = 0.f;
}

__global__ void convert6(const float* __restrict__ s0, const float* __restrict__ s1,
                         const float* __restrict__ s2, const float* __restrict__ s3,
                         const float* __restrict__ s4, const float* __restrict__ s5,
                         _Float16* __restrict__ dst)
{
    const int WN4 = (1 << 20) / 4;
    int i = blockIdx.x * blockDim.x + threadIdx.x;
    int stride = gridDim.x * blockDim.x;
    for (; i < 6 * WN4; i += stride) {
        int seg = i / WN4;
        int off = i - seg * WN4;
        const float* sp = seg == 0 ? s0 : seg == 1 ? s1 : seg == 2 ? s2
                        : seg == 3 ? s3 : seg == 4 ? s4 : s5;
        float4 v = reinterpret_cast<const float4*>(sp)[off];
        _Float16 h4o[4] = {(_Float16)v.x, (_Float16)v.y, (_Float16)v.z, (_Float16)v.w};
        u64 bits;
        __builtin_memcpy(&bits, h4o, 8);
        reinterpret_cast<u64*>(dst)[i] = bits;
    }
}

extern "C" void kernel_launch(void* const* d_in, const int* in_sizes, int n_in,
                              void* d_out, int out_size, void* d_ws, size_t ws_size,
                              hipStream_t stream)
{
    const float* x        = (const float*)d_in[0];
    const float* enc_Wih0 = (const float*)d_in[1];
    const float* enc_Whh0 = (const float*)d_in[2];
    const float* enc_b0   = (const float*)d_in[3];
    const float* enc_Wih1 = (const float*)d_in[4];
    const float* enc_Whh1 = (const float*)d_in[5];
    const float* enc_b1   = (const float*)d_in[6];
    const float* dec_Wih0 = (const float*)d_in[7];
    const float* dec_Whh0 = (const float*)d_in[8];
    const float* dec_b0   = (const float*)d_in[9];
    const float* dec_Wih1 = (const float*)d_in[10];
    const float* dec_Whh1 = (const float*)d_in[11];
    const float* dec_b1   = (const float*)d_in[12];
    const float* head_W   = (const float*)d_in[13];
    const float* head_b   = (const float*)d_in[14];
    float* out = (float*)d_out;

    const size_t MB = 1u << 20;
    char* ws = (char*)d_ws;
    const size_t PERSIST_NEED = 177 * MB;

    if (ws_size >= PERSIST_NEED) {
        float*    c0     = (float*)(ws + 0 * MB);
        float*    c1     = (float*)(ws + 2 * MB);
        uint32_t* flags  = (uint32_t*)(ws + 4 * MB);     // 16 x 64 u32
        _Float16* wf16   = (_Float16*)(ws + 5 * MB);     // 12MB
        _Float16* h0base = (_Float16*)(ws + 17 * MB);    // 80MB
        _Float16* h1base = (_Float16*)(ws + 97 * MB);    // 80MB

        zero_kernel<<<1, 256, 0, stream>>>((float*)flags, 1024);
        convert6<<<2048, NTHR, 0, stream>>>(enc_Whh0, enc_Wih1, enc_Whh1,
                                            dec_Whh0, dec_Wih1, dec_Whh1, wf16);

        PP P;
        P.x = x;
        P.eWih0 = enc_Wih0; P.eb0 = enc_b0; P.eb1 = enc_b1;
        P.dWih0 = dec_Wih0; P.db0 = dec_b0; P.db1 = dec_b1;
        P.headW = head_W; P.headb = head_b;
        P.eWhh0f = wf16 + 0 * (1 << 20);
        P.eWih1f = wf16 + 1 * (1 << 20);
        P.eWhh1f = wf16 + 2 * (1 << 20);
        P.dWhh0f = wf16 + 3 * (1 << 20);
        P.dWih1f = wf16 + 4 * (1 << 20);
        P.dWhh1f = wf16 + 5 * (1 << 20);
        P.c0 = c0; P.c1 = c1;
        P.h0base = h0base; P.h1base = h1base;
        P.flags = flags;
        P.outp = out;

        lstm_persist5<<<dim3(512), dim3(NTHR), 0, stream>>>(P);
        return;
    }

    // fallback: round-6 multi-launch
    float*    c0     = (float*)(ws + 0 * MB);
    float*    c1     = (float*)(ws + 2 * MB);
    _Float16* h0a    = (_Float16*)(ws + 4 * MB);
    _Float16* h0b    = (_Float16*)(ws + 5 * MB);
    _Float16* h1a    = (_Float16*)(ws + 6 * MB);
    _Float16* h1b    = (_Float16*)(ws + 7 * MB);
    u64*      accA   = (u64*)(ws + 8 * MB);
    u64*      accB   = (u64*)(ws + 8 * MB + 65536);
    _Float16* wf16   = (_Float16*)(ws + 9 * MB);

    convert6<<<2048, NTHR, 0, stream>>>(enc_Whh0, enc_Wih1, enc_Whh1,
                                        dec_Whh0, dec_Wih1, dec_Whh1, wf16);
    _Float16* eWhh0f = wf16 + 0 * (1 << 20);
    _Float16* eWih1f = wf16 + 1 * (1 << 20);
    _Float16* eWhh1f = wf16 + 2 * (1 << 20);
    _Float16* dWhh0f = wf16 + 3 * (1 << 20);
    _Float16* dWih1f = wf16 + 4 * (1 << 20);
    _Float16* dWhh1f = wf16 + 5 * (1 << 20);

    for (int d = 0; d <= T_SRC; ++d)
        enc_step<<<1024, NTHR, 0, stream>>>(d, x, enc_Wih0, enc_b0, enc_b1,
                                            eWhh0f, eWih1f, eWhh1f,
                                            c0, c1, h0a, h0b, h1a, h1b);

    for (int t = 0; t < T_TGT; ++t) {
        dec0_step<<<512, NTHR, 0, stream>>>(t, x, dec_Wih0, dec_b0, head_b,
                                            dWhh0f, c0, h0a, h0b, accA, accB, out);
        dec1_step<<<512, NTHR, 0, stream>>>(t, dec_b1, head_W, dWih1f, dWhh1f,
                                            c1, h0a, h0b, h1a, h1b, accA, accB);
    }
    final_out<<<(B * I_DIM + NTHR - 1) / NTHR, NTHR, 0, stream>>>(
        (T_TGT - 1) & 1 ? accB : accA, head_b, out);
}

// Round 11
// 1869.064 us; speedup vs baseline: 1.7065x; 1.4443x over previous
//
#include <hip/hip_runtime.h>
#include <math.h>
#include <stdint.h>

#define B 1024
#define H 512
#define T_SRC 50
#define T_TGT 30
#define I_DIM 4
#define NTHR 256

typedef _Float16 half8 __attribute__((ext_vector_type(8)));
typedef float f32x4 __attribute__((ext_vector_type(4)));
typedef unsigned long long u64;

#define GLOBAL_AS __attribute__((address_space(1)))
#define LDS_AS    __attribute__((address_space(3)))

#define SCALE_F 1099511627776.0f          // 2^40 (fallback head fixed-point)

__device__ __forceinline__ float sigm(float x) { return 1.0f / (1.0f + expf(-x)); }

__device__ __forceinline__ void cohs(u64* p, u64 v) {
    __hip_atomic_store(p, v, __ATOMIC_RELAXED, __HIP_MEMORY_SCOPE_AGENT);
}

// ---------------- verified GEMM+cell core (rounds 2/4/6) ----------------
// gates = A1@W1^T (+A2@W2^T) [f16 MFMA fp32-acc] (+ x@Wih^T + b); LSTM cell.
// coh=1: h store via agent write-through (for intra-dispatch visibility).
__device__ __forceinline__ void layer_core(
    char* smem,
    const _Float16* __restrict__ A1, const _Float16* __restrict__ W1,
    const _Float16* __restrict__ A2, const _Float16* __restrict__ W2,
    int npass, int zero_c,
    const float* __restrict__ xg, int xstride,
    const float* __restrict__ xl,
    const float* __restrict__ Wih,
    const float* __restrict__ bias,
    float* __restrict__ c_st, _Float16* __restrict__ h_out,
    _Float16* pH,
    int m0, int kc0, int coh)
{
    const int tid = threadIdx.x;
    const int w = tid >> 6, l = tid & 63;
    const int mw = (w & 1) * 32, nw = (w >> 1) * 32;

    f32x4 acc[2][2] = {};
    const int nt = npass * 8;

    size_t aoff[2], boff[2];
    int ldsw[2];
#pragma unroll
    for (int q = 0; q < 2; ++q) {
        int rowq = (w * 2 + q) * 8 + (l >> 3);
        int gsrc = (l & 7) ^ (rowq & 7);
        aoff[q] = (size_t)(m0 + rowq) * H + gsrc * 8;
        int jg = (rowq >> 4) * H + kc0 + (rowq & 15);
        boff[q] = (size_t)jg * H + gsrc * 8;
        ldsw[q] = (w * 2 + q) * 1024;
    }

    auto stage = [&](int t, int cur) {
        const _Float16* Ap = (t < 8) ? A1 : A2;
        const _Float16* Wp = (t < 8) ? W1 : W2;
        const int koff = (t & 7) * 64;
        char* dbase = smem + cur * 16384;
#pragma unroll
        for (int q = 0; q < 2; ++q) {
            __builtin_amdgcn_global_load_lds(
                (const GLOBAL_AS uint32_t*)(Ap + aoff[q] + koff),
                (LDS_AS uint32_t*)(dbase + ldsw[q]), 16, 0, 0);
            __builtin_amdgcn_global_load_lds(
                (const GLOBAL_AS uint32_t*)(Wp + boff[q] + koff),
                (LDS_AS uint32_t*)(dbase + 8192 + ldsw[q]), 16, 0, 0);
        }
    };

    if (nt > 0) {
        stage(0, 0);
        __syncthreads();
        int cur = 0;
        for (int t = 0; t < nt; ++t) {
            if (t + 1 < nt) stage(t + 1, cur ^ 1);
            const char* ab = smem + cur * 16384;
            const char* bb = ab + 8192;
#pragma unroll
            for (int ks = 0; ks < 2; ++ks) {
                half8 af[2], bf[2];
#pragma unroll
                for (int f = 0; f < 2; ++f) {
                    const int gg = ks * 4 + (l >> 4);
                    const int m = mw + f * 16 + (l & 15);
                    af[f] = *reinterpret_cast<const half8*>(ab + m * 128 + ((gg ^ (m & 7)) * 16));
                    const int n = nw + f * 16 + (l & 15);
                    bf[f] = *reinterpret_cast<const half8*>(bb + n * 128 + ((gg ^ (n & 7)) * 16));
                }
#pragma unroll
                for (int fm = 0; fm < 2; ++fm)
#pragma unroll
                    for (int fn = 0; fn < 2; ++fn)
                        acc[fm][fn] = __builtin_amdgcn_mfma_f32_16x16x32_f16(
                            af[fm], bf[fn], acc[fm][fn], 0, 0, 0);
            }
            __syncthreads();
            cur ^= 1;
        }
    }

    float* Gs = reinterpret_cast<float*>(smem);
#pragma unroll
    for (int fm = 0; fm < 2; ++fm)
#pragma unroll
        for (int fn = 0; fn < 2; ++fn)
#pragma unroll
            for (int r = 0; r < 4; ++r)
                Gs[(mw + fm * 16 + (l >> 4) * 4 + r) * 65 + nw + fn * 16 + (l & 15)] =
                    acc[fm][fn][r];
    __syncthreads();

    {
        const int em = tid & 63;
        const int ekq = tid >> 6;
        const int brow = m0 + em;
        const int kbase = kc0 + ekq * 4;
        float g4[4][4];
#pragma unroll
        for (int gate = 0; gate < 4; ++gate)
#pragma unroll
            for (int j = 0; j < 4; ++j)
                g4[gate][j] = Gs[em * 65 + gate * 16 + ekq * 4 + j]
                            + bias[gate * H + kbase + j];
        if (Wih != nullptr) {
            float x0, x1, x2, x3;
            if (xl != nullptr) {
                x0 = xl[em * 4 + 0]; x1 = xl[em * 4 + 1];
                x2 = xl[em * 4 + 2]; x3 = xl[em * 4 + 3];
            } else {
                const float* xr = xg + (size_t)brow * xstride;
                x0 = xr[0]; x1 = xr[1]; x2 = xr[2]; x3 = xr[3];
            }
#pragma unroll
            for (int gate = 0; gate < 4; ++gate)
#pragma unroll
                for (int j = 0; j < 4; ++j) {
                    const float* wv = &Wih[(size_t)(gate * H + kbase + j) * 4];
                    g4[gate][j] += x0 * wv[0] + x1 * wv[1] + x2 * wv[2] + x3 * wv[3];
                }
        }
        size_t cidx = (size_t)brow * H + kbase;
        f32x4 cold;
        if (zero_c) { cold[0] = cold[1] = cold[2] = cold[3] = 0.f; }
        else        { cold = *reinterpret_cast<const f32x4*>(&c_st[cidx]); }
        f32x4 cnew;
        _Float16 h4[4];
#pragma unroll
        for (int j = 0; j < 4; ++j) {
            float cn = sigm(g4[1][j]) * cold[j] + sigm(g4[0][j]) * tanhf(g4[2][j]);
            cnew[j] = cn;
            h4[j] = (_Float16)(sigm(g4[3][j]) * tanhf(cn));
        }
        *reinterpret_cast<f32x4*>(&c_st[cidx]) = cnew;
        u64 hbits;
        __builtin_memcpy(&hbits, h4, 8);
        if (coh) cohs(reinterpret_cast<u64*>(h_out + cidx), hbits);
        else     *reinterpret_cast<u64*>(h_out + cidx) = hbits;
        if (pH != nullptr) {
#pragma unroll
            for (int j = 0; j < 4; ++j)
                pH[em * 16 + ekq * 4 + j] = h4[j];
        }
    }
}

// r7-verified group barrier (target=32, counter pre-zeroed in-graph).
__device__ __forceinline__ void grp_barrier32(uint32_t* cnt)
{
    __syncthreads();   // drains vmcnt(0): phase-A write-through h at coherence point
    if (threadIdx.x == 0) {
        __hip_atomic_fetch_add(cnt, 1u, __ATOMIC_RELAXED, __HIP_MEMORY_SCOPE_AGENT);
        while (__hip_atomic_load(cnt, __ATOMIC_RELAXED, __HIP_MEMORY_SCOPE_AGENT) < 32u)
            __builtin_amdgcn_s_sleep(2);
    }
    __syncthreads();
    asm volatile("" ::: "memory");
}

// ---------------- encoder (round-6 verified, unchanged) ----------------
__global__ __launch_bounds__(NTHR)
void enc_step(int d, const float* __restrict__ x,
              const float* __restrict__ eWih0, const float* __restrict__ eb0,
              const float* __restrict__ eb1,
              const _Float16* __restrict__ eWhh0, const _Float16* __restrict__ eWih1,
              const _Float16* __restrict__ eWhh1,
              float* __restrict__ c0, float* __restrict__ c1,
              _Float16* h0a, _Float16* h0b, _Float16* h1a, _Float16* h1b)
{
    __shared__ __align__(16) char smem[32768];
    const int bx = blockIdx.x;
    const int role = bx >> 9, sub = bx & 511;
    const int m0 = (sub & 15) * 64, kc0 = (sub >> 4) * 16;
    _Float16* h0[2] = {h0a, h0b};
    _Float16* h1[2] = {h1a, h1b};

    if (role == 0) {
        const int t = d;
        if (t >= T_SRC) return;
        const _Float16* A1 = (t == 0) ? nullptr : h0[(t - 1) & 1];
        layer_core(smem, A1, eWhh0, nullptr, nullptr, (t == 0) ? 0 : 1, (t == 0) ? 1 : 0,
                   x + (size_t)t * I_DIM, T_SRC * I_DIM, nullptr,
                   eWih0, eb0, c0, h0[t & 1], nullptr, m0, kc0, 0);
    } else {
        const int t = d - 1;
        if (t < 0) return;
        if (t == 0)
            layer_core(smem, h0[0], eWih1, nullptr, nullptr, 1, 1,
                       nullptr, 0, nullptr, nullptr, eb1, c1, h1[0], nullptr, m0, kc0, 0);
        else
            layer_core(smem, h0[t & 1], eWih1, h1[(t - 1) & 1], eWhh1, 2, 0,
                       nullptr, 0, nullptr, nullptr, eb1, c1, h1[t & 1], nullptr, m0, kc0, 0);
    }
}

// ---------------- fused decoder step: L0 -> group barrier -> L1 ----------------
// L0 (t>0): gates = h0prev@Whh0^T + h1prev@Weq^T + db0pc (head folded into Weq).
// h0(t) written write-through to a FRESH buffer; phase B reads it (fresh-address
// plain loads) after the 32-block group barrier — r7-verified protocol.
__global__ __launch_bounds__(NTHR)
void dec_fused(int t, const float* __restrict__ x,
               const float* __restrict__ dWih0, const float* __restrict__ db0,
               const float* __restrict__ db0pc, const float* __restrict__ db1,
               const _Float16* __restrict__ Weqf,
               const _Float16* __restrict__ dWhh0f,
               const _Float16* __restrict__ dWih1f, const _Float16* __restrict__ dWhh1f,
               float* __restrict__ c0, float* __restrict__ c1,
               const _Float16* __restrict__ h0prev, const _Float16* __restrict__ h1prev,
               _Float16* __restrict__ h0cur, _Float16* __restrict__ h1cur,
               uint32_t* __restrict__ cnt)
{
    __shared__ __align__(16) char smem[32768];
    const int sub = blockIdx.x;
    const int m0 = (sub & 15) * 64, kc0 = (sub >> 4) * 16;
    const int g = sub & 15;

    // phase A: L0(t)
    if (t == 0)
        layer_core(smem, h0prev, dWhh0f, nullptr, nullptr, 1, 0,
                   x + (size_t)(T_SRC - 1) * I_DIM, T_SRC * I_DIM, nullptr,
                   dWih0, db0, c0, h0cur, nullptr, m0, kc0, 1);
    else
        layer_core(smem, h0prev, dWhh0f, h1prev, Weqf, 2, 0,
                   nullptr, 0, nullptr, nullptr, db0pc, c0, h0cur, nullptr, m0, kc0, 1);

    grp_barrier32(cnt + g);

    // phase B: L1(t) — pass order identical to rounds 2-7 (h0@Wih1, h1prev@Whh1)
    layer_core(smem, h0cur, dWih1f, h1prev, dWhh1f, 2, 0,
               nullptr, 0, nullptr, nullptr, db1, c1, h1cur, nullptr, m0, kc0, 0);
}

// out[:, t, :] for all t from the stored h1(t) buffers (one dispatch).
__global__ __launch_bounds__(NTHR)
void final_head(const _Float16* __restrict__ h1base, const float* __restrict__ W,
                const float* __restrict__ hb, float* __restrict__ outp)
{
    const int t = blockIdx.x, chunk = blockIdx.y;
    const _Float16* h1 = h1base + ((size_t)t << 19);
    const int row = chunk * 64 + (threadIdx.x >> 2), o = threadIdx.x & 3;
    const _Float16* hr = h1 + (size_t)row * H;
    const float* wr = W + o * H;
    float s = 0.f;
#pragma unroll 4
    for (int k = 0; k < H; k += 8) {
        half8 hv = *reinterpret_cast<const half8*>(hr + k);
#pragma unroll
        for (int j = 0; j < 8; ++j) s += (float)hv[j] * wr[k + j];
    }
    outp[((size_t)row * T_TGT + t) * I_DIM + o] = s + hb[o];
}

// ---------------- fallback decoder pieces (round-6 verified) ----------------
__global__ __launch_bounds__(NTHR)
void dec0_step(int t, const float* __restrict__ x,
               const float* __restrict__ dWih0, const float* __restrict__ db0,
               const float* __restrict__ headb,
               const _Float16* __restrict__ dWhh0,
               float* __restrict__ c0,
               _Float16* h0a, _Float16* h0b,
               u64* __restrict__ accA, u64* __restrict__ accB,
               float* __restrict__ outp)
{
    __shared__ __align__(16) char smem[32768];
    __shared__ float decbuf[64 * 4];
    const int sub = blockIdx.x;
    const int m0 = (sub & 15) * 64, kc0 = (sub >> 4) * 16;
    const int ntile = sub >> 4;
    const int tid = threadIdx.x;
    _Float16* h0[2] = {h0a, h0b};

    u64* accCur = (t & 1) ? accB : accA;
    u64* accPrev = (t & 1) ? accA : accB;

    const int row = tid >> 2, o = tid & 3;
    if (ntile == 0)
        accCur[(size_t)(m0 + row) * I_DIM + o] = 0ull;

    const float* xg = nullptr;
    const float* xl = nullptr;
    if (t == 0) {
        xg = x + (size_t)(T_SRC - 1) * I_DIM;
    } else {
        long long v = (long long)accPrev[(size_t)(m0 + row) * I_DIM + o];
        float val = (float)((double)v * (1.0 / 1099511627776.0)) + headb[o];
        decbuf[tid] = val;
        if (ntile == 0)
            outp[((size_t)(m0 + row) * T_TGT + (t - 1)) * I_DIM + o] = val;
        xl = decbuf;
        __syncthreads();
    }

    const _Float16* A1 = (t == 0) ? h0[1] : h0[(t - 1) & 1];
    layer_core(smem, A1, dWhh0, nullptr, nullptr, 1, 0,
               xg, T_SRC * I_DIM, xl, dWih0, db0, c0, h0[t & 1], nullptr, m0, kc0, 0);
}

__global__ __launch_bounds__(NTHR)
void dec1_step(int t, const float* __restrict__ db1,
               const float* __restrict__ headW,
               const _Float16* __restrict__ dWih1, const _Float16* __restrict__ dWhh1,
               float* __restrict__ c1,
               _Float16* h0a, _Float16* h0b, _Float16* h1a, _Float16* h1b,
               u64* __restrict__ accA, u64* __restrict__ accB)
{
    __shared__ __align__(16) char smem[32768];
    __shared__ _Float16 pH[64 * 16];
    const int sub = blockIdx.x;
    const int m0 = (sub & 15) * 64, kc0 = (sub >> 4) * 16;
    const int tid = threadIdx.x;
    _Float16* h0[2] = {h0a, h0b};
    _Float16* h1[2] = {h1a, h1b};

    const _Float16* h1prev = (t == 0) ? h1[1] : h1[(t - 1) & 1];
    layer_core(smem, h0[t & 1], dWih1, h1prev, dWhh1, 2, 0,
               nullptr, 0, nullptr, nullptr, db1, c1, h1[t & 1], pH, m0, kc0, 0);
    __syncthreads();

    u64* accCur = (t & 1) ? accB : accA;
    const int em = tid >> 2, o = tid & 3;
    float s = 0.f;
#pragma unroll
    for (int j = 0; j < 16; ++j)
        s += (float)pH[em * 16 + j] * headW[(size_t)o * H + kc0 + j];
    long long qv = (long long)(s * SCALE_F);
    atomicAdd(accCur + ((size_t)(m0 + em) * I_DIM + o), (u64)qv);
}

__global__ __launch_bounds__(NTHR)
void final_out(const u64* __restrict__ accLast, const float* __restrict__ headb,
               float* __restrict__ outp)
{
    int i = blockIdx.x * blockDim.x + threadIdx.x;
    if (i < B * I_DIM) {
        int b = i >> 2, o = i & 3;
        long long v = (long long)accLast[i];
        float val = (float)((double)v * (1.0 / 1099511627776.0)) + headb[o];
        outp[((size_t)b * T_TGT + (T_TGT - 1)) * I_DIM + o] = val;
    }
}

// ---------------- setup kernels ----------------
__global__ void zero_kernel(float* __restrict__ ptr, int n)
{
    int i = blockIdx.x * blockDim.x + threadIdx.x;
    int stride = gridDim.x * blockDim.x;
    for (; i < n; i += stride) ptr[i] = 0.f;
}

__global__ void convert6(const float* __restrict__ s0, const float* __restrict__ s1,
                         const float* __restrict__ s2, const float* __restrict__ s3,
                         const float* __restrict__ s4, const float* __restrict__ s5,
                         _Float16* __restrict__ dst)
{
    const int WN4 = (1 << 20) / 4;
    int i = blockIdx.x * blockDim.x + threadIdx.x;
    int stride = gridDim.x * blockDim.x;
    for (; i < 6 * WN4; i += stride) {
        int seg = i / WN4;
        int off = i - seg * WN4;
        const float* sp = seg == 0 ? s0 : seg == 1 ? s1 : seg == 2 ? s2
                        : seg == 3 ? s3 : seg == 4 ? s4 : s5;
        float4 v = reinterpret_cast<const float4*>(sp)[off];
        _Float16 h4o[4] = {(_Float16)v.x, (_Float16)v.y, (_Float16)v.z, (_Float16)v.w};
        u64 bits;
        __builtin_memcpy(&bits, h4o, 8);
        reinterpret_cast<u64*>(dst)[i] = bits;
    }
}

// Weq[j][k] = sum_i Wih0[j][i]*headW[i][k] (f16); db0pc[j] = db0[j] + Wih0[j]·headb
__global__ void weq_build(const float* __restrict__ Wih0, const float* __restrict__ headW,
                          const float* __restrict__ headb, const float* __restrict__ db0,
                          _Float16* __restrict__ Weqf, float* __restrict__ db0pc)
{
    int i = blockIdx.x * blockDim.x + threadIdx.x;
    int stride = gridDim.x * blockDim.x;
    for (int idx = i; idx < 2048 * 512; idx += stride) {
        int j = idx >> 9, k = idx & 511;
        const float* wr = &Wih0[(size_t)j * 4];
        float s = wr[0] * headW[0 * H + k] + wr[1] * headW[1 * H + k]
                + wr[2] * headW[2 * H + k] + wr[3] * headW[3 * H + k];
        Weqf[idx] = (_Float16)s;
    }
    for (int j = i; j < 2048; j += stride) {
        const float* wr = &Wih0[(size_t)j * 4];
        db0pc[j] = db0[j] + wr[0] * headb[0] + wr[1] * headb[1]
                 + wr[2] * headb[2] + wr[3] * headb[3];
    }
}

extern "C" void kernel_launch(void* const* d_in, const int* in_sizes, int n_in,
                              void* d_out, int out_size, void* d_ws, size_t ws_size,
                              hipStream_t stream)
{
    const float* x        = (const float*)d_in[0];
    const float* enc_Wih0 = (const float*)d_in[1];
    const float* enc_Whh0 = (const float*)d_in[2];
    const float* enc_b0   = (const float*)d_in[3];
    const float* enc_Wih1 = (const float*)d_in[4];
    const float* enc_Whh1 = (const float*)d_in[5];
    const float* enc_b1   = (const float*)d_in[6];
    const float* dec_Wih0 = (const float*)d_in[7];
    const float* dec_Whh0 = (const float*)d_in[8];
    const float* dec_b0   = (const float*)d_in[9];
    const float* dec_Wih1 = (const float*)d_in[10];
    const float* dec_Whh1 = (const float*)d_in[11];
    const float* dec_b1   = (const float*)d_in[12];
    const float* head_W   = (const float*)d_in[13];
    const float* head_b   = (const float*)d_in[14];
    float* out = (float*)d_out;

    const size_t MB = 1u << 20;
    char* ws = (char*)d_ws;
    const size_t PRIMARY_NEED = 88 * MB;

    if (ws_size >= PRIMARY_NEED) {
        float*    c0     = (float*)(ws + 0 * MB);
        float*    c1     = (float*)(ws + 2 * MB);
        uint32_t* dflags = (uint32_t*)(ws + 4 * MB);       // 30*16 u32, zeroed
        _Float16* wf16   = (_Float16*)(ws + 5 * MB);       // 12 MB
        _Float16* Weqf   = (_Float16*)(ws + 17 * MB);      // 2 MB
        float*    db0pc  = (float*)(ws + 19 * MB);         // 8 KB
        _Float16* h0a    = (_Float16*)(ws + 20 * MB);
        _Float16* h0b    = (_Float16*)(ws + 21 * MB);
        _Float16* h1a    = (_Float16*)(ws + 22 * MB);
        _Float16* h1b    = (_Float16*)(ws + 23 * MB);
        _Float16* h0d    = (_Float16*)(ws + 24 * MB);      // 30 x 1 MB
        _Float16* h1d    = (_Float16*)(ws + 54 * MB);      // 30 x 1 MB

        _Float16* eWhh0f = wf16 + 0 * (1 << 20);
        _Float16* eWih1f = wf16 + 1 * (1 << 20);
        _Float16* eWhh1f = wf16 + 2 * (1 << 20);
        _Float16* dWhh0f = wf16 + 3 * (1 << 20);
        _Float16* dWih1f = wf16 + 4 * (1 << 20);
        _Float16* dWhh1f = wf16 + 5 * (1 << 20);

        zero_kernel<<<2, 256, 0, stream>>>((float*)dflags, 30 * 16);
        convert6<<<2048, NTHR, 0, stream>>>(enc_Whh0, enc_Wih1, enc_Whh1,
                                            dec_Whh0, dec_Wih1, dec_Whh1, wf16);
        weq_build<<<2048, NTHR, 0, stream>>>(dec_Wih0, head_W, head_b, dec_b0,
                                             Weqf, db0pc);

        for (int d = 0; d <= T_SRC; ++d)
            enc_step<<<1024, NTHR, 0, stream>>>(d, x, enc_Wih0, enc_b0, enc_b1,
                                                eWhh0f, eWih1f, eWhh1f,
                                                c0, c1, h0a, h0b, h1a, h1b);

        for (int t = 0; t < T_TGT; ++t) {
            const _Float16* h0prev = (t == 0) ? h0b : h0d + ((size_t)(t - 1) << 19);
            const _Float16* h1prev = (t == 0) ? h1b : h1d + ((size_t)(t - 1) << 19);
            dec_fused<<<512, NTHR, 0, stream>>>(t, x, dec_Wih0, dec_b0, db0pc, dec_b1,
                                                Weqf, dWhh0f, dWih1f, dWhh1f,
                                                c0, c1, h0prev, h1prev,
                                                h0d + ((size_t)t << 19),
                                                h1d + ((size_t)t << 19),
                                                dflags + t * 16);
        }
        final_head<<<dim3(T_TGT, 16), NTHR, 0, stream>>>(h1d, head_W, head_b, out);
        return;
    }

    // ---------------- fallback: round-6 verified multi-launch ----------------
    float*    c0     = (float*)(ws + 0 * MB);
    float*    c1     = (float*)(ws + 2 * MB);
    _Float16* h0a    = (_Float16*)(ws + 4 * MB);
    _Float16* h0b    = (_Float16*)(ws + 5 * MB);
    _Float16* h1a    = (_Float16*)(ws + 6 * MB);
    _Float16* h1b    = (_Float16*)(ws + 7 * MB);
    u64*      accA   = (u64*)(ws + 8 * MB);
    u64*      accB   = (u64*)(ws + 8 * MB + 65536);
    _Float16* wf16   = (_Float16*)(ws + 9 * MB);

    convert6<<<2048, NTHR, 0, stream>>>(enc_Whh0, enc_Wih1, enc_Whh1,
                                        dec_Whh0, dec_Wih1, dec_Whh1, wf16);
    _Float16* eWhh0f = wf16 + 0 * (1 << 20);
    _Float16* eWih1f = wf16 + 1 * (1 << 20);
    _Float16* eWhh1f = wf16 + 2 * (1 << 20);
    _Float16* dWhh0f = wf16 + 3 * (1 << 20);
    _Float16* dWih1f = wf16 + 4 * (1 << 20);
    _Float16* dWhh1f = wf16 + 5 * (1 << 20);

    for (int d = 0; d <= T_SRC; ++d)
        enc_step<<<1024, NTHR, 0, stream>>>(d, x, enc_Wih0, enc_b0, enc_b1,
                                            eWhh0f, eWih1f, eWhh1f,
                                            c0, c1, h0a, h0b, h1a, h1b);

    for (int t = 0; t < T_TGT; ++t) {
        dec0_step<<<512, NTHR, 0, stream>>>(t, x, dec_Wih0, dec_b0, head_b,
                                            dWhh0f, c0, h0a, h0b, accA, accB, out);
        dec1_step<<<512, NTHR, 0, stream>>>(t, dec_b1, head_W, dWih1f, dWhh1f,
                                            c1, h0a, h0b, h1a, h1b, accA, accB);
    }
    final_out<<<(B * I_DIM + NTHR - 1) / NTHR, NTHR, 0, stream>>>(
        (T_TGT - 1) & 1 ? accB : accA, head_b, out);
}

// Round 12
// 1571.375 us; speedup vs baseline: 2.0298x; 1.1894x over previous
//
#include <hip/hip_runtime.h>
#include <math.h>
#include <stdint.h>

#define B 1024
#define H 512
#define T_SRC 50
#define T_TGT 30
#define I_DIM 4
#define NTHR 256

typedef _Float16 half8 __attribute__((ext_vector_type(8)));
typedef float f32x4 __attribute__((ext_vector_type(4)));
typedef unsigned long long u64;

#define GLOBAL_AS __attribute__((address_space(1)))
#define LDS_AS    __attribute__((address_space(3)))

#define SCALE_F 1099511627776.0f          // 2^40 (head fixed-point)
#define SMEM_BYTES 49152                  // 3 x 16KB ring

__device__ __forceinline__ float sigm(float x) { return 1.0f / (1.0f + expf(-x)); }

// XCD-pinned mapping: blocks sharing a weight slice (ntile) land on one XCD
// (empirical bx%8 round-robin; perf heuristic only — correctness unaffected).
__device__ __forceinline__ void sub_map(int sub, int& m0, int& kc0, int& ntile)
{
    const int xcd = sub & 7, j = sub >> 3;      // j in [0,64)
    ntile = xcd * 4 + (j >> 4);                 // [0,32): pinned to xcd
    const int g = j & 15;                       // [0,16)
    m0 = g * 64;
    kc0 = ntile * 16;
}

// ---------------- GEMM+cell core: r6-verified arithmetic + r10-verified
// counted-vmcnt 3-buffer ring (2 tiles in flight across raw s_barrier).
// Per-wave loads/tile = 4; vmcnt retires in order (m135), so vmcnt(4) with
// older stray VMEM ops outstanding still means "tile t fully landed".
__device__ __forceinline__ void layer_core(
    char* smem,
    const _Float16* __restrict__ A1, const _Float16* __restrict__ W1,
    const _Float16* __restrict__ A2, const _Float16* __restrict__ W2,
    int npass, int zero_c,
    const float* __restrict__ xg, int xstride,
    const float* __restrict__ xl,
    const float* __restrict__ Wih,
    const float* __restrict__ bias,
    float* __restrict__ c_st, _Float16* __restrict__ h_out,
    _Float16* pH,
    int m0, int kc0)
{
    const int tid = threadIdx.x;
    const int w = tid >> 6, l = tid & 63;
    const int mw = (w & 1) * 32, nw = (w >> 1) * 32;

    f32x4 acc[2][2] = {};
    const int nt = npass * 8;

    size_t aoff[2], boff[2];
    int ldsw[2];
#pragma unroll
    for (int q = 0; q < 2; ++q) {
        int rowq = (w * 2 + q) * 8 + (l >> 3);
        int gsrc = (l & 7) ^ (rowq & 7);
        aoff[q] = (size_t)(m0 + rowq) * H + gsrc * 8;
        int jg = (rowq >> 4) * H + kc0 + (rowq & 15);
        boff[q] = (size_t)jg * H + gsrc * 8;
        ldsw[q] = (w * 2 + q) * 1024;
    }

    auto issue = [&](int t, int buf) {
        const _Float16* Ap = (t < 8) ? A1 : A2;
        const _Float16* Wp = (t < 8) ? W1 : W2;
        const int koff = (t & 7) * 64;
        char* dbase = smem + buf * 16384;
#pragma unroll
        for (int q = 0; q < 2; ++q) {
            __builtin_amdgcn_global_load_lds(
                (const GLOBAL_AS uint32_t*)(Ap + aoff[q] + koff),
                (LDS_AS uint32_t*)(dbase + ldsw[q]), 16, 0, 0);
            __builtin_amdgcn_global_load_lds(
                (const GLOBAL_AS uint32_t*)(Wp + boff[q] + koff),
                (LDS_AS uint32_t*)(dbase + 8192 + ldsw[q]), 16, 0, 0);
        }
    };

    if (nt > 0) {
        issue(0, 0);
        issue(1, 1);
        int cbuf = 0, ibuf = 2;
        for (int t = 0; t < nt; ++t) {
            if (t < nt - 1) asm volatile("s_waitcnt vmcnt(4)" ::: "memory");
            else            asm volatile("s_waitcnt vmcnt(0)" ::: "memory");
            __builtin_amdgcn_s_barrier();   // all waves' tile-t chunks in LDS
            if (t + 2 < nt) {               // buffer (t+2)%3 = (t-1)%3: its
                issue(t + 2, ibuf);         // reads were consumed last iter
                ibuf = (ibuf == 2) ? 0 : ibuf + 1;
            }
            const char* ab = smem + cbuf * 16384;
            const char* bb = ab + 8192;
#pragma unroll
            for (int ks = 0; ks < 2; ++ks) {
                half8 af[2], bf[2];
#pragma unroll
                for (int f = 0; f < 2; ++f) {
                    const int gg = ks * 4 + (l >> 4);
                    const int m = mw + f * 16 + (l & 15);
                    af[f] = *reinterpret_cast<const half8*>(ab + m * 128 + ((gg ^ (m & 7)) * 16));
                    const int n = nw + f * 16 + (l & 15);
                    bf[f] = *reinterpret_cast<const half8*>(bb + n * 128 + ((gg ^ (n & 7)) * 16));
                }
#pragma unroll
                for (int fm = 0; fm < 2; ++fm)
#pragma unroll
                    for (int fn = 0; fn < 2; ++fn)
                        acc[fm][fn] = __builtin_amdgcn_mfma_f32_16x16x32_f16(
                            af[fm], bf[fn], acc[fm][fn], 0, 0, 0);
            }
            cbuf = (cbuf == 2) ? 0 : cbuf + 1;
        }
        __syncthreads();   // all reads done before smem is reused for Gs
    }

    float* Gs = reinterpret_cast<float*>(smem);   // 16.6KB, fits in 48KB ring
#pragma unroll
    for (int fm = 0; fm < 2; ++fm)
#pragma unroll
        for (int fn = 0; fn < 2; ++fn)
#pragma unroll
            for (int r = 0; r < 4; ++r)
                Gs[(mw + fm * 16 + (l >> 4) * 4 + r) * 65 + nw + fn * 16 + (l & 15)] =
                    acc[fm][fn][r];
    __syncthreads();

    {
        const int em = tid & 63;
        const int ekq = tid >> 6;
        const int brow = m0 + em;
        const int kbase = kc0 + ekq * 4;
        float g4[4][4];
#pragma unroll
        for (int gate = 0; gate < 4; ++gate)
#pragma unroll
            for (int j = 0; j < 4; ++j)
                g4[gate][j] = Gs[em * 65 + gate * 16 + ekq * 4 + j]
                            + bias[gate * H + kbase + j];
        if (Wih != nullptr) {
            float x0, x1, x2, x3;
            if (xl != nullptr) {
                x0 = xl[em * 4 + 0]; x1 = xl[em * 4 + 1];
                x2 = xl[em * 4 + 2]; x3 = xl[em * 4 + 3];
            } else {
                const float* xr = xg + (size_t)brow * xstride;
                x0 = xr[0]; x1 = xr[1]; x2 = xr[2]; x3 = xr[3];
            }
#pragma unroll
            for (int gate = 0; gate < 4; ++gate)
#pragma unroll
                for (int j = 0; j < 4; ++j) {
                    const float* wv = &Wih[(size_t)(gate * H + kbase + j) * 4];
                    g4[gate][j] += x0 * wv[0] + x1 * wv[1] + x2 * wv[2] + x3 * wv[3];
                }
        }
        size_t cidx = (size_t)brow * H + kbase;
        f32x4 cold;
        if (zero_c) { cold[0] = cold[1] = cold[2] = cold[3] = 0.f; }
        else        { cold = *reinterpret_cast<const f32x4*>(&c_st[cidx]); }
        f32x4 cnew;
        _Float16 h4[4];
#pragma unroll
        for (int j = 0; j < 4; ++j) {
            float cn = sigm(g4[1][j]) * cold[j] + sigm(g4[0][j]) * tanhf(g4[2][j]);
            cnew[j] = cn;
            h4[j] = (_Float16)(sigm(g4[3][j]) * tanhf(cn));
        }
        *reinterpret_cast<f32x4*>(&c_st[cidx]) = cnew;
        u64 hbits;
        __builtin_memcpy(&hbits, h4, 8);
        *reinterpret_cast<u64*>(h_out + cidx) = hbits;
        if (pH != nullptr) {
#pragma unroll
            for (int j = 0; j < 4; ++j)
                pH[em * 16 + ekq * 4 + j] = h4[j];
        }
    }
}

// ---------------- encoder: dispatch d = L0(d) || L1(d-1) (r6 structure) ----------------
__global__ __launch_bounds__(NTHR)
void enc_step(int d, const float* __restrict__ x,
              const float* __restrict__ eWih0, const float* __restrict__ eb0,
              const float* __restrict__ eb1,
              const _Float16* __restrict__ eWhh0, const _Float16* __restrict__ eWih1,
              const _Float16* __restrict__ eWhh1,
              float* __restrict__ c0, float* __restrict__ c1,
              _Float16* h0a, _Float16* h0b, _Float16* h1a, _Float16* h1b)
{
    __shared__ __align__(16) char smem[SMEM_BYTES];
    const int bx = blockIdx.x;
    const int role = bx >> 9, sub = bx & 511;
    int m0, kc0, ntile;
    sub_map(sub, m0, kc0, ntile);
    _Float16* h0[2] = {h0a, h0b};
    _Float16* h1[2] = {h1a, h1b};

    if (role == 0) {
        const int t = d;
        if (t >= T_SRC) return;
        const _Float16* A1 = (t == 0) ? nullptr : h0[(t - 1) & 1];
        layer_core(smem, A1, eWhh0, nullptr, nullptr, (t == 0) ? 0 : 1, (t == 0) ? 1 : 0,
                   x + (size_t)t * I_DIM, T_SRC * I_DIM, nullptr,
                   eWih0, eb0, c0, h0[t & 1], nullptr, m0, kc0);
    } else {
        const int t = d - 1;
        if (t < 0) return;
        if (t == 0)
            layer_core(smem, h0[0], eWih1, nullptr, nullptr, 1, 1,
                       nullptr, 0, nullptr, nullptr, eb1, c1, h1[0], nullptr, m0, kc0);
        else
            layer_core(smem, h0[t & 1], eWih1, h1[(t - 1) & 1], eWhh1, 2, 0,
                       nullptr, 0, nullptr, nullptr, eb1, c1, h1[t & 1], nullptr, m0, kc0);
    }
}

// ---------------- decoder (r6 structure: fixed-point atomic head) ----------------
__global__ __launch_bounds__(NTHR)
void dec0_step(int t, const float* __restrict__ x,
               const float* __restrict__ dWih0, const float* __restrict__ db0,
               const float* __restrict__ headb,
               const _Float16* __restrict__ dWhh0,
               float* __restrict__ c0,
               _Float16* h0a, _Float16* h0b,
               u64* __restrict__ accA, u64* __restrict__ accB,
               float* __restrict__ outp)
{
    __shared__ __align__(16) char smem[SMEM_BYTES];
    __shared__ float decbuf[64 * 4];
    const int sub = blockIdx.x;
    int m0, kc0, ntile;
    sub_map(sub, m0, kc0, ntile);
    const int tid = threadIdx.x;
    _Float16* h0[2] = {h0a, h0b};

    u64* accCur = (t & 1) ? accB : accA;
    u64* accPrev = (t & 1) ? accA : accB;

    const int row = tid >> 2, o = tid & 3;
    if (ntile == 0)
        accCur[(size_t)(m0 + row) * I_DIM + o] = 0ull;

    const float* xg = nullptr;
    const float* xl = nullptr;
    if (t == 0) {
        xg = x + (size_t)(T_SRC - 1) * I_DIM;
    } else {
        long long v = (long long)accPrev[(size_t)(m0 + row) * I_DIM + o];
        float val = (float)((double)v * (1.0 / 1099511627776.0)) + headb[o];
        decbuf[tid] = val;
        if (ntile == 0)
            outp[((size_t)(m0 + row) * T_TGT + (t - 1)) * I_DIM + o] = val;
        xl = decbuf;
        __syncthreads();
    }

    const _Float16* A1 = (t == 0) ? h0[1] : h0[(t - 1) & 1];
    layer_core(smem, A1, dWhh0, nullptr, nullptr, 1, 0,
               xg, T_SRC * I_DIM, xl, dWih0, db0, c0, h0[t & 1], nullptr, m0, kc0);
}

__global__ __launch_bounds__(NTHR)
void dec1_step(int t, const float* __restrict__ db1,
               const float* __restrict__ headW,
               const _Float16* __restrict__ dWih1, const _Float16* __restrict__ dWhh1,
               float* __restrict__ c1,
               _Float16* h0a, _Float16* h0b, _Float16* h1a, _Float16* h1b,
               u64* __restrict__ accA, u64* __restrict__ accB)
{
    __shared__ __align__(16) char smem[SMEM_BYTES];
    __shared__ _Float16 pH[64 * 16];
    const int sub = blockIdx.x;
    int m0, kc0, ntile;
    sub_map(sub, m0, kc0, ntile);
    const int tid = threadIdx.x;
    _Float16* h0[2] = {h0a, h0b};
    _Float16* h1[2] = {h1a, h1b};

    const _Float16* h1prev = (t == 0) ? h1[1] : h1[(t - 1) & 1];
    layer_core(smem, h0[t & 1], dWih1, h1prev, dWhh1, 2, 0,
               nullptr, 0, nullptr, nullptr, db1, c1, h1[t & 1], pH, m0, kc0);
    __syncthreads();

    u64* accCur = (t & 1) ? accB : accA;
    const int em = tid >> 2, o = tid & 3;
    float s = 0.f;
#pragma unroll
    for (int j = 0; j < 16; ++j)
        s += (float)pH[em * 16 + j] * headW[(size_t)o * H + kc0 + j];
    long long qv = (long long)(s * SCALE_F);
    atomicAdd(accCur + ((size_t)(m0 + em) * I_DIM + o), (u64)qv);
}

__global__ __launch_bounds__(NTHR)
void final_out(const u64* __restrict__ accLast, const float* __restrict__ headb,
               float* __restrict__ outp)
{
    int i = blockIdx.x * blockDim.x + threadIdx.x;
    if (i < B * I_DIM) {
        int b = i >> 2, o = i & 3;
        long long v = (long long)accLast[i];
        float val = (float)((double)v * (1.0 / 1099511627776.0)) + headb[o];
        outp[((size_t)b * T_TGT + (T_TGT - 1)) * I_DIM + o] = val;
    }
}

__global__ void convert6(const float* __restrict__ s0, const float* __restrict__ s1,
                         const float* __restrict__ s2, const float* __restrict__ s3,
                         const float* __restrict__ s4, const float* __restrict__ s5,
                         _Float16* __restrict__ dst)
{
    const int WN4 = (1 << 20) / 4;
    int i = blockIdx.x * blockDim.x + threadIdx.x;
    int stride = gridDim.x * blockDim.x;
    for (; i < 6 * WN4; i += stride) {
        int seg = i / WN4;
        int off = i - seg * WN4;
        const float* sp = seg == 0 ? s0 : seg == 1 ? s1 : seg == 2 ? s2
                        : seg == 3 ? s3 : seg == 4 ? s4 : s5;
        float4 v = reinterpret_cast<const float4*>(sp)[off];
        _Float16 h4o[4] = {(_Float16)v.x, (_Float16)v.y, (_Float16)v.z, (_Float16)v.w};
        u64 bits;
        __builtin_memcpy(&bits, h4o, 8);
        reinterpret_cast<u64*>(dst)[i] = bits;
    }
}

extern "C" void kernel_launch(void* const* d_in, const int* in_sizes, int n_in,
                              void* d_out, int out_size, void* d_ws, size_t ws_size,
                              hipStream_t stream)
{
    const float* x        = (const float*)d_in[0];
    const float* enc_Wih0 = (const float*)d_in[1];
    const float* enc_Whh0 = (const float*)d_in[2];
    const float* enc_b0   = (const float*)d_in[3];
    const float* enc_Wih1 = (const float*)d_in[4];
    const float* enc_Whh1 = (const float*)d_in[5];
    const float* enc_b1   = (const float*)d_in[6];
    const float* dec_Wih0 = (const float*)d_in[7];
    const float* dec_Whh0 = (const float*)d_in[8];
    const float* dec_b0   = (const float*)d_in[9];
    const float* dec_Wih1 = (const float*)d_in[10];
    const float* dec_Whh1 = (const float*)d_in[11];
    const float* dec_b1   = (const float*)d_in[12];
    const float* head_W   = (const float*)d_in[13];
    const float* head_b   = (const float*)d_in[14];
    float* out = (float*)d_out;

    const size_t MB = 1u << 20;
    char* ws = (char*)d_ws;
    float*    c0     = (float*)(ws + 0 * MB);
    float*    c1     = (float*)(ws + 2 * MB);
    _Float16* h0a    = (_Float16*)(ws + 4 * MB);
    _Float16* h0b    = (_Float16*)(ws + 5 * MB);
    _Float16* h1a    = (_Float16*)(ws + 6 * MB);
    _Float16* h1b    = (_Float16*)(ws + 7 * MB);
    u64*      accA   = (u64*)(ws + 8 * MB);
    u64*      accB   = (u64*)(ws + 8 * MB + 65536);
    _Float16* wf16   = (_Float16*)(ws + 9 * MB);

    convert6<<<2048, NTHR, 0, stream>>>(enc_Whh0, enc_Wih1, enc_Whh1,
                                        dec_Whh0, dec_Wih1, dec_Whh1, wf16);
    _Float16* eWhh0f = wf16 + 0 * (1 << 20);
    _Float16* eWih1f = wf16 + 1 * (1 << 20);
    _Float16* eWhh1f = wf16 + 2 * (1 << 20);
    _Float16* dWhh0f = wf16 + 3 * (1 << 20);
    _Float16* dWih1f = wf16 + 4 * (1 << 20);
    _Float16* dWhh1f = wf16 + 5 * (1 << 20);

    // encoder: dispatch d runs L0(d) || L1(d-1)
    for (int d = 0; d <= T_SRC; ++d)
        enc_step<<<1024, NTHR, 0, stream>>>(d, x, enc_Wih0, enc_b0, enc_b1,
                                            eWhh0f, eWih1f, eWhh1f,
                                            c0, c1, h0a, h0b, h1a, h1b);

    // decoder: 2 dispatches per step; head folded into dec1 (fixed-point atomics)
    for (int t = 0; t < T_TGT; ++t) {
        dec0_step<<<512, NTHR, 0, stream>>>(t, x, dec_Wih0, dec_b0, head_b,
                                            dWhh0f, c0, h0a, h0b, accA, accB, out);
        dec1_step<<<512, NTHR, 0, stream>>>(t, dec_b1, head_W, dWih1f, dWhh1f,
                                            c1, h0a, h0b, h1a, h1b, accA, accB);
    }
    final_out<<<(B * I_DIM + NTHR - 1) / NTHR, NTHR, 0, stream>>>(
        (T_TGT - 1) & 1 ? accB : accA, head_b, out);
}